// Round 1
// baseline (555.981 us; speedup 1.0000x reference)
//
#include <hip/hip_runtime.h>
#include <hip/hip_bf16.h>
#include <math.h>

#define BB 2
#define TT 1024
#define SS 1024
#define DD 1024
#define HH 16
#define DH 64

typedef __attribute__((ext_vector_type(8))) short bf16x8;
typedef __attribute__((ext_vector_type(4))) float f32x4;
typedef unsigned short ushort_t;

#define AS3(p) ((__attribute__((address_space(3))) unsigned int*)(p))
#define AS1(p) ((const __attribute__((address_space(1))) unsigned int*)(p))

__device__ __forceinline__ unsigned short f2b(float f) {
    union { float f; unsigned u; } x; x.f = f;
    unsigned r = x.u + 0x7FFFu + ((x.u >> 16) & 1u);
    return (unsigned short)(r >> 16);
}

// ---------------------------------------------------------------------------
// fp32 -> bf16 conversion kernels
// ---------------------------------------------------------------------------
__global__ __launch_bounds__(256) void cvt3_kernel(
    const float* __restrict__ a, const float* __restrict__ b, const float* __restrict__ c,
    ushort_t* __restrict__ oa, ushort_t* __restrict__ ob, ushort_t* __restrict__ oc)
{
    const float* src = (blockIdx.y == 0) ? a : (blockIdx.y == 1) ? b : c;
    ushort_t* dst    = (blockIdx.y == 0) ? oa : (blockIdx.y == 1) ? ob : oc;
    size_t i = ((size_t)blockIdx.x * 256 + threadIdx.x) * 8;
    float4 v0 = *(const float4*)&src[i];
    float4 v1 = *(const float4*)&src[i + 4];
    uint4 o;
    o.x = f2b(v0.x) | ((unsigned)f2b(v0.y) << 16);
    o.y = f2b(v0.z) | ((unsigned)f2b(v0.w) << 16);
    o.z = f2b(v1.x) | ((unsigned)f2b(v1.y) << 16);
    o.w = f2b(v1.z) | ((unsigned)f2b(v1.w) << 16);
    *(uint4*)&dst[i] = o;
}

__global__ __launch_bounds__(256) void cvt4_kernel(
    const float* __restrict__ a, const float* __restrict__ b,
    const float* __restrict__ c, const float* __restrict__ d,
    ushort_t* __restrict__ oa, ushort_t* __restrict__ ob,
    ushort_t* __restrict__ oc, ushort_t* __restrict__ od)
{
    const float* src = (blockIdx.y == 0) ? a : (blockIdx.y == 1) ? b : (blockIdx.y == 2) ? c : d;
    ushort_t* dst    = (blockIdx.y == 0) ? oa : (blockIdx.y == 1) ? ob : (blockIdx.y == 2) ? oc : od;
    size_t i = ((size_t)blockIdx.x * 256 + threadIdx.x) * 8;
    float4 v0 = *(const float4*)&src[i];
    float4 v1 = *(const float4*)&src[i + 4];
    uint4 o;
    o.x = f2b(v0.x) | ((unsigned)f2b(v0.y) << 16);
    o.y = f2b(v0.z) | ((unsigned)f2b(v0.w) << 16);
    o.z = f2b(v1.x) | ((unsigned)f2b(v1.y) << 16);
    o.w = f2b(v1.z) | ((unsigned)f2b(v1.w) << 16);
    *(uint4*)&dst[i] = o;
}

// ---------------------------------------------------------------------------
// 128x128 bf16 MFMA GEMM mainloop: D = A (MxK) . Bw^T (N x K), both K-contig.
// BK=32, global_load_lds width-16 staging, XOR chunk swizzle (2-way max).
// ---------------------------------------------------------------------------
__device__ __forceinline__ void gemm128_mainloop(
    const ushort_t* __restrict__ A,   // pre-offset to (bm,0), row stride K
    const ushort_t* __restrict__ Bw,  // pre-offset to (bn,0), row stride K
    int K, ushort_t* Asm, ushort_t* Bsm, f32x4 acc[4][4])
{
    const int tid = threadIdx.x;
    const int wave = tid >> 6, lane = tid & 63;
    const int sr = lane >> 2;                        // row within 16-row group
    const int gc = (lane & 3) ^ ((lane >> 3) & 3);   // swizzled global chunk
    const int l15 = lane & 15, q = lane >> 4;
    const int mblk = (wave >> 1) * 64, nblk = (wave & 1) * 64;

    for (int k0 = 0; k0 < K; k0 += 32) {
        #pragma unroll
        for (int o = 0; o < 2; o++) {
            int r0 = (wave * 2 + o) * 16;
            __builtin_amdgcn_global_load_lds(AS1(A + (size_t)(r0 + sr) * K + k0 + gc * 8),
                                             AS3(Asm + r0 * 32), 16, 0, 0);
            __builtin_amdgcn_global_load_lds(AS1(Bw + (size_t)(r0 + sr) * K + k0 + gc * 8),
                                             AS3(Bsm + r0 * 32), 16, 0, 0);
        }
        __syncthreads();

        bf16x8 av[4], bv[4];
        #pragma unroll
        for (int mi = 0; mi < 4; mi++) {
            int r = mblk + mi * 16 + l15;
            av[mi] = *(const bf16x8*)&Asm[r * 32 + (q ^ ((r >> 1) & 3)) * 8];
        }
        #pragma unroll
        for (int ni = 0; ni < 4; ni++) {
            int r = nblk + ni * 16 + l15;
            bv[ni] = *(const bf16x8*)&Bsm[r * 32 + (q ^ ((r >> 1) & 3)) * 8];
        }
        #pragma unroll
        for (int mi = 0; mi < 4; mi++)
            #pragma unroll
            for (int ni = 0; ni < 4; ni++)
                acc[mi][ni] = __builtin_amdgcn_mfma_f32_16x16x32_bf16(av[mi], bv[ni], acc[mi][ni], 0, 0, 0);
        __syncthreads();
    }
}

// Fused Q/K/V projections: z picks which. Output bf16 (B,T,D).
__global__ __launch_bounds__(256) void proj_gemm(
    const ushort_t* __restrict__ qb, const ushort_t* __restrict__ kb, const ushort_t* __restrict__ vb,
    const ushort_t* __restrict__ Wqb, const ushort_t* __restrict__ Wkb, const ushort_t* __restrict__ Wvb,
    const float* __restrict__ bq, const float* __restrict__ bk, const float* __restrict__ bv,
    ushort_t* __restrict__ qh, ushort_t* __restrict__ kh, ushort_t* __restrict__ vh)
{
    __shared__ ushort_t Asm[128 * 32];
    __shared__ ushort_t Bsm[128 * 32];
    const int z = blockIdx.z;
    const ushort_t* A = (z == 0) ? qb : (z == 1) ? kb : vb;
    const ushort_t* W = (z == 0) ? Wqb : (z == 1) ? Wkb : Wvb;
    const float* bias = (z == 0) ? bq : (z == 1) ? bk : bv;
    ushort_t* Y = (z == 0) ? qh : (z == 1) ? kh : vh;

    const int bm = blockIdx.y * 128, bn = blockIdx.x * 128;
    f32x4 acc[4][4];
    #pragma unroll
    for (int i = 0; i < 4; i++)
        #pragma unroll
        for (int j = 0; j < 4; j++) acc[i][j] = (f32x4)(0.f);

    gemm128_mainloop(A + (size_t)bm * DD, W + (size_t)bn * DD, DD, Asm, Bsm, acc);

    const int lane = threadIdx.x & 63, wave = threadIdx.x >> 6;
    const int mblk = (wave >> 1) * 64, nblk = (wave & 1) * 64;
    const int l15 = lane & 15, q = lane >> 4;
    #pragma unroll
    for (int mi = 0; mi < 4; mi++) {
        #pragma unroll
        for (int ni = 0; ni < 4; ni++) {
            int col = bn + nblk + ni * 16 + l15;
            float bcol = bias[col];
            #pragma unroll
            for (int r = 0; r < 4; r++) {
                int row = bm + mblk + mi * 16 + q * 4 + r;
                Y[(size_t)row * DD + col] = f2b(acc[mi][ni][r] + bcol);
            }
        }
    }
}

// Output projection: bf16 in, fp32 out + bias.
__global__ __launch_bounds__(256) void oproj_gemm(
    const ushort_t* __restrict__ A, const ushort_t* __restrict__ W,
    const float* __restrict__ bias, float* __restrict__ Y)
{
    __shared__ ushort_t Asm[128 * 32];
    __shared__ ushort_t Bsm[128 * 32];
    const int bm = blockIdx.y * 128, bn = blockIdx.x * 128;
    f32x4 acc[4][4];
    #pragma unroll
    for (int i = 0; i < 4; i++)
        #pragma unroll
        for (int j = 0; j < 4; j++) acc[i][j] = (f32x4)(0.f);

    gemm128_mainloop(A + (size_t)bm * DD, W + (size_t)bn * DD, DD, Asm, Bsm, acc);

    const int lane = threadIdx.x & 63, wave = threadIdx.x >> 6;
    const int mblk = (wave >> 1) * 64, nblk = (wave & 1) * 64;
    const int l15 = lane & 15, q = lane >> 4;
    #pragma unroll
    for (int mi = 0; mi < 4; mi++) {
        #pragma unroll
        for (int ni = 0; ni < 4; ni++) {
            int col = bn + nblk + ni * 16 + l15;
            float bcol = bias[col];
            #pragma unroll
            for (int r = 0; r < 4; r++) {
                int row = bm + mblk + mi * 16 + q * 4 + r;
                Y[(size_t)row * DD + col] = acc[mi][ni][r] + bcol;
            }
        }
    }
}

// ---------------------------------------------------------------------------
// V transpose: vh (B,S,H,DH) bf16 -> vT (B,H,DH,S) bf16
// ---------------------------------------------------------------------------
__global__ __launch_bounds__(256) void transpose_v(
    const ushort_t* __restrict__ vh, ushort_t* __restrict__ vT)
{
    __shared__ ushort_t Ls[64][72];
    const int s0 = blockIdx.x * 64;
    const int bh = blockIdx.y;
    const int b = bh >> 4, h = bh & 15;
    const int tid = threadIdx.x;
    const int r = tid >> 2, c16 = (tid & 3) * 16;

    const ushort_t* src = &vh[((size_t)(b * SS + s0 + r) * HH + h) * DH + c16];
    uint4 u0 = *(const uint4*)src;
    uint4 u1 = *(const uint4*)(src + 8);
    ushort_t tmp[16];
    *(uint4*)&tmp[0] = u0; *(uint4*)&tmp[8] = u1;
    #pragma unroll
    for (int j = 0; j < 16; j++) Ls[c16 + j][r] = tmp[j];
    __syncthreads();

    const int dh = r;
    uint4 w0 = *(const uint4*)&Ls[dh][c16];
    uint4 w1 = *(const uint4*)&Ls[dh][c16 + 8];
    ushort_t* dst = &vT[((size_t)bh * DH + dh) * SS + s0 + c16];
    *(uint4*)dst = w0;
    *(uint4*)(dst + 8) = w1;
}

// ---------------------------------------------------------------------------
// Fused scores + clip + causal mask + softmax + tanh-bias + renorm + write.
// One block = 64 t-rows of one (b,h), full S sweep, two passes over s-tiles:
//   Pass A: MFMA scores -> online (rowmax m, sum p = P, sum p*scale = W)
//   Pass B: recompute scores (bitwise identical), write p*scale/(W+1e-9*P).
// Each wave owns 16 rows -> all row reductions are shfl_xor within 16 lanes.
// Fully-masked s-tiles are zero-filled with vectorized stores up front.
// ---------------------------------------------------------------------------
__global__ __launch_bounds__(256) void attn_fused(
    const ushort_t* __restrict__ qh, const ushort_t* __restrict__ kh,
    const float* __restrict__ attn_bias, const float* __restrict__ bias_scale_p,
    float* __restrict__ attn)
{
    __shared__ ushort_t Ks[64 * 64];   // 8 KB K tile (64 s-rows x 64 dh, XOR-swizzled)

    const int ti = (int)gridDim.x - 1 - (int)blockIdx.x;  // heavy blocks launch first
    const int bh = blockIdx.y;
    const int b = bh >> 4, h = bh & 15;
    const int t0 = ti * 64;
    const int nS = ti + 1;            // # of (partially) unmasked s-tiles

    const int tid = threadIdx.x;
    const int wave = tid >> 6, lane = tid & 63;
    const int l15 = lane & 15, q = lane >> 4;
    const int sr8 = lane >> 3;
    const int gc8 = (lane & 7) ^ sr8;
    const float bscale = bias_scale_p[0];

    // zero-fill fully-masked tiles (stores drain under later compute)
    for (int si = nS; si < SS / 64; si++) {
        const int s0 = si * 64;
        #pragma unroll
        for (int i = 0; i < 4; i++) {
            int row = i * 16 + (tid >> 4);
            float4 z = make_float4(0.f, 0.f, 0.f, 0.f);
            *(float4*)&attn[((size_t)bh * TT + t0 + row) * SS + s0 + (tid & 15) * 4] = z;
        }
    }

    // Q fragments for this wave's 16 rows (A-operand: row = l15, k-chunk = q)
    bf16x8 aq[2];
    {
        const int row = t0 + wave * 16 + l15;
        const ushort_t* src = &qh[((size_t)(b * TT + row) * HH + h) * DH + q * 8];
        aq[0] = *(const bf16x8*)src;
        aq[1] = *(const bf16x8*)(src + 32);
    }

    const int tr = t0 + wave * 16 + q * 4;   // + r gives this lane's global t-row

    float m[4], P[4], W[4];
    #pragma unroll
    for (int r = 0; r < 4; r++) { m[r] = -INFINITY; P[r] = 0.f; W[r] = 0.f; }

    // ---------------- Pass A: online stats ----------------
    for (int si = 0; si < nS; si++) {
        const int s0 = si * 64;
        #pragma unroll
        for (int o = 0; o < 2; o++) {
            int r0 = wave * 16 + o * 8;
            __builtin_amdgcn_global_load_lds(
                AS1(kh + ((size_t)(b * SS + s0 + r0 + sr8) * HH + h) * DH + gc8 * 8),
                AS3(Ks + r0 * 64), 16, 0, 0);
        }
        __syncthreads();

        f32x4 acc[4];
        #pragma unroll
        for (int ni = 0; ni < 4; ni++) acc[ni] = (f32x4)(0.f);
        #pragma unroll
        for (int ks = 0; ks < 2; ks++) {
            #pragma unroll
            for (int ni = 0; ni < 4; ni++) {
                int r = ni * 16 + l15;
                bf16x8 bv = *(const bf16x8*)&Ks[r * 64 + ((ks * 4 + q) ^ (r & 7)) * 8];
                acc[ni] = __builtin_amdgcn_mfma_f32_16x16x32_bf16(aq[ks], bv, acc[ni], 0, 0, 0);
            }
        }
        __syncthreads();   // Ks consumed; safe to restage next iter

        // tile row-max (masked)
        float tmax[4];
        #pragma unroll
        for (int r = 0; r < 4; r++) tmax[r] = -INFINITY;
        #pragma unroll
        for (int ni = 0; ni < 4; ni++) {
            int s = s0 + ni * 16 + l15;
            #pragma unroll
            for (int r = 0; r < 4; r++) {
                float v = fminf(fmaxf(acc[ni][r] * 0.125f, -80.f), 80.f);
                if (s <= tr + r) tmax[r] = fmaxf(tmax[r], v);
            }
        }
        #pragma unroll
        for (int off = 1; off < 16; off <<= 1) {
            #pragma unroll
            for (int r = 0; r < 4; r++)
                tmax[r] = fmaxf(tmax[r], __shfl_xor(tmax[r], off));
        }

        // online rescale (m==-inf twice -> f=1, no NaN)
        float pP[4], pW[4];
        #pragma unroll
        for (int r = 0; r < 4; r++) {
            float mn = fmaxf(m[r], tmax[r]);
            float f = (mn == m[r]) ? 1.f : __expf(m[r] - mn);
            P[r] *= f; W[r] *= f; m[r] = mn;
            pP[r] = 0.f; pW[r] = 0.f;
        }
        #pragma unroll
        for (int ni = 0; ni < 4; ni++) {
            int s = s0 + ni * 16 + l15;
            #pragma unroll
            for (int r = 0; r < 4; r++) {
                if (s <= tr + r) {
                    float v = fminf(fmaxf(acc[ni][r] * 0.125f, -80.f), 80.f);
                    float p = __expf(v - m[r]);
                    float bvv = attn_bias[((size_t)bh * TT + tr + r) * SS + s];
                    float e = __expf(-2.f * fabsf(bvv));
                    float th = copysignf((1.f - e) / (1.f + e), bvv);
                    float sc = fmaxf(1.f + bscale * th, 1e-9f);
                    pP[r] += p;
                    pW[r] += p * sc;
                }
            }
        }
        #pragma unroll
        for (int off = 1; off < 16; off <<= 1) {
            #pragma unroll
            for (int r = 0; r < 4; r++) {
                pP[r] += __shfl_xor(pP[r], off);
                pW[r] += __shfl_xor(pW[r], off);
            }
        }
        #pragma unroll
        for (int r = 0; r < 4; r++) { P[r] += pP[r]; W[r] += pW[r]; }
    }

    // final_i = p_i*sc_i / (W + 1e-9*P)   [== softmax*scale renormalized + eps]
    float inv[4];
    #pragma unroll
    for (int r = 0; r < 4; r++) inv[r] = 1.f / (W[r] + 1e-9f * P[r]);

    // ---------------- Pass B: recompute + write ----------------
    for (int si = 0; si < nS; si++) {
        const int s0 = si * 64;
        #pragma unroll
        for (int o = 0; o < 2; o++) {
            int r0 = wave * 16 + o * 8;
            __builtin_amdgcn_global_load_lds(
                AS1(kh + ((size_t)(b * SS + s0 + r0 + sr8) * HH + h) * DH + gc8 * 8),
                AS3(Ks + r0 * 64), 16, 0, 0);
        }
        __syncthreads();

        f32x4 acc[4];
        #pragma unroll
        for (int ni = 0; ni < 4; ni++) acc[ni] = (f32x4)(0.f);
        #pragma unroll
        for (int ks = 0; ks < 2; ks++) {
            #pragma unroll
            for (int ni = 0; ni < 4; ni++) {
                int r = ni * 16 + l15;
                bf16x8 bv = *(const bf16x8*)&Ks[r * 64 + ((ks * 4 + q) ^ (r & 7)) * 8];
                acc[ni] = __builtin_amdgcn_mfma_f32_16x16x32_bf16(aq[ks], bv, acc[ni], 0, 0, 0);
            }
        }
        __syncthreads();

        #pragma unroll
        for (int ni = 0; ni < 4; ni++) {
            int s = s0 + ni * 16 + l15;
            #pragma unroll
            for (int r = 0; r < 4; r++) {
                float res = 0.f;
                if (s <= tr + r) {
                    float v = fminf(fmaxf(acc[ni][r] * 0.125f, -80.f), 80.f);
                    float p = __expf(v - m[r]);
                    float bvv = attn_bias[((size_t)bh * TT + tr + r) * SS + s];
                    float e = __expf(-2.f * fabsf(bvv));
                    float th = copysignf((1.f - e) / (1.f + e), bvv);
                    float sc = fmaxf(1.f + bscale * th, 1e-9f);
                    res = p * sc * inv[r];
                }
                attn[((size_t)bh * TT + tr + r) * SS + s] = res;
            }
        }
    }
}

// ---------------------------------------------------------------------------
// AV: ao[b,t,h*64+dh] = sum_s attn[bh,t,s] * V[s,dh].  64t x 64dh per block.
// A staged fp32->bf16 manually; V staged from vT via global_load_lds.
// attn has exact zeros for s>t, so full diagonal tiles are safe.
// ---------------------------------------------------------------------------
__global__ __launch_bounds__(256) void av_mfma(
    const float* __restrict__ attn, const ushort_t* __restrict__ vT,
    ushort_t* __restrict__ ao)
{
    __shared__ ushort_t Asm[64 * 32];
    __shared__ ushort_t Vsm[64 * 32];

    const int tb = blockIdx.x;
    const int bh = blockIdx.y;
    const int b = bh >> 4, h = bh & 15;
    const int t0 = tb * 64;
    const int nsteps = (tb + 1) * 2;

    const int tid = threadIdx.x;
    const int wave = tid >> 6, lane = tid & 63;
    const int ar = tid >> 2, aq = tid & 3;
    const int aslot = aq ^ ((ar >> 1) & 3);
    const int vsr = lane >> 2;
    const int vgc = (lane & 3) ^ ((lane >> 3) & 3);
    const int l15 = lane & 15, q = lane >> 4;

    f32x4 acc[4];
    #pragma unroll
    for (int i = 0; i < 4; i++) acc[i] = (f32x4)(0.f);

    for (int st = 0; st < nsteps; st++) {
        const int s0 = st * 32;
        {   // stage A (fp32 -> bf16)
            const float* src = &attn[((size_t)bh * TT + t0 + ar) * SS + s0 + aq * 8];
            float4 u0 = *(const float4*)src;
            float4 u1 = *(const float4*)(src + 4);
            uint4 o;
            o.x = f2b(u0.x) | ((unsigned)f2b(u0.y) << 16);
            o.y = f2b(u0.z) | ((unsigned)f2b(u0.w) << 16);
            o.z = f2b(u1.x) | ((unsigned)f2b(u1.y) << 16);
            o.w = f2b(u1.z) | ((unsigned)f2b(u1.w) << 16);
            *(uint4*)&Asm[ar * 32 + aslot * 8] = o;
        }
        {   // stage V rows wave*16..+15
            int r0 = wave * 16;
            __builtin_amdgcn_global_load_lds(
                AS1(vT + ((size_t)bh * DH + r0 + vsr) * SS + s0 + vgc * 8),
                AS3(Vsm + r0 * 32), 16, 0, 0);
        }
        __syncthreads();

        bf16x8 a0, bv[4];
        {
            int r = wave * 16 + l15;
            a0 = *(const bf16x8*)&Asm[r * 32 + (q ^ ((r >> 1) & 3)) * 8];
        }
        #pragma unroll
        for (int ni = 0; ni < 4; ni++) {
            int r = ni * 16 + l15;
            bv[ni] = *(const bf16x8*)&Vsm[r * 32 + (q ^ ((r >> 1) & 3)) * 8];
        }
        #pragma unroll
        for (int ni = 0; ni < 4; ni++)
            acc[ni] = __builtin_amdgcn_mfma_f32_16x16x32_bf16(a0, bv[ni], acc[ni], 0, 0, 0);
        __syncthreads();
    }

    #pragma unroll
    for (int ni = 0; ni < 4; ni++) {
        int dh = ni * 16 + l15;
        #pragma unroll
        for (int r = 0; r < 4; r++) {
            int t = t0 + wave * 16 + q * 4 + r;
            ao[(size_t)(b * TT + t) * DD + h * DH + dh] = f2b(acc[ni][r]);
        }
    }
}

// ---------------------------------------------------------------------------
extern "C" void kernel_launch(void* const* d_in, const int* in_sizes, int n_in,
                              void* d_out, int out_size, void* d_ws, size_t ws_size,
                              hipStream_t stream)
{
    const float* q   = (const float*)d_in[0];
    const float* k   = (const float*)d_in[1];
    const float* v   = (const float*)d_in[2];
    const float* attn_bias = (const float*)d_in[4];
    const float* Wq = (const float*)d_in[5];
    const float* bq = (const float*)d_in[6];
    const float* Wk = (const float*)d_in[7];
    const float* bk = (const float*)d_in[8];
    const float* Wv = (const float*)d_in[9];
    const float* bv = (const float*)d_in[10];
    const float* Wo = (const float*)d_in[11];
    const float* bo = (const float*)d_in[12];
    const float* bscale = (const float*)d_in[13];

    // ws layout (32 MB total, with aliasing):
    char* base = (char*)d_ws;
    ushort_t* qb  = (ushort_t*)(base + (0ull << 20));   // 4 MB, later vT
    ushort_t* kb  = (ushort_t*)(base + (4ull << 20));   // 4 MB, later ao
    ushort_t* vb  = (ushort_t*)(base + (8ull << 20));   // 4 MB
    ushort_t* Wqb = (ushort_t*)(base + (12ull << 20));  // 2 MB
    ushort_t* Wkb = (ushort_t*)(base + (14ull << 20));  // 2 MB
    ushort_t* Wvb = (ushort_t*)(base + (16ull << 20));  // 2 MB
    ushort_t* Wob = (ushort_t*)(base + (18ull << 20));  // 2 MB
    ushort_t* qhb = (ushort_t*)(base + (20ull << 20));  // 4 MB
    ushort_t* khb = (ushort_t*)(base + (24ull << 20));  // 4 MB
    ushort_t* vhb = (ushort_t*)(base + (28ull << 20));  // 4 MB
    ushort_t* vT  = qb;   // alias: qb dead after proj_gemm
    ushort_t* aob = kb;   // alias: kb dead after proj_gemm

    float* out  = (float*)d_out;
    float* attn = out + (size_t)BB * TT * DD;

    cvt3_kernel<<<dim3(1024, 3), 256, 0, stream>>>(q, k, v, qb, kb, vb);
    cvt4_kernel<<<dim3(512, 4), 256, 0, stream>>>(Wq, Wk, Wv, Wo, Wqb, Wkb, Wvb, Wob);
    proj_gemm<<<dim3(8, 16, 3), 256, 0, stream>>>(qb, kb, vb, Wqb, Wkb, Wvb,
                                                  bq, bk, bv, qhb, khb, vhb);
    transpose_v<<<dim3(16, 32), 256, 0, stream>>>(vhb, vT);
    attn_fused<<<dim3(16, 32), 256, 0, stream>>>(qhb, khb, attn_bias, bscale, attn);
    av_mfma<<<dim3(16, 32), 256, 0, stream>>>(attn, vT, aob);
    oproj_gemm<<<dim3(8, 16), 256, 0, stream>>>(aob, Wob, bo, out);
}

// Round 2
// 374.870 us; speedup vs baseline: 1.4831x; 1.4831x over previous
//
#include <hip/hip_runtime.h>
#include <hip/hip_bf16.h>
#include <math.h>

#define BB 2
#define TT 1024
#define SS 1024
#define DD 1024
#define HH 16
#define DH 64

typedef __attribute__((ext_vector_type(8))) short bf16x8;
typedef __attribute__((ext_vector_type(4))) float f32x4;
typedef unsigned short ushort_t;

#define AS3(p) ((__attribute__((address_space(3))) unsigned int*)(p))
#define AS1(p) ((const __attribute__((address_space(1))) unsigned int*)(p))

__device__ __forceinline__ unsigned short f2b(float f) {
    union { float f; unsigned u; } x; x.f = f;
    unsigned r = x.u + 0x7FFFu + ((x.u >> 16) & 1u);
    return (unsigned short)(r >> 16);
}

// ---------------------------------------------------------------------------
// fp32 -> bf16 conversion kernels
// ---------------------------------------------------------------------------
__global__ __launch_bounds__(256) void cvt3_kernel(
    const float* __restrict__ a, const float* __restrict__ b, const float* __restrict__ c,
    ushort_t* __restrict__ oa, ushort_t* __restrict__ ob, ushort_t* __restrict__ oc)
{
    const float* src = (blockIdx.y == 0) ? a : (blockIdx.y == 1) ? b : c;
    ushort_t* dst    = (blockIdx.y == 0) ? oa : (blockIdx.y == 1) ? ob : oc;
    size_t i = ((size_t)blockIdx.x * 256 + threadIdx.x) * 8;
    float4 v0 = *(const float4*)&src[i];
    float4 v1 = *(const float4*)&src[i + 4];
    uint4 o;
    o.x = f2b(v0.x) | ((unsigned)f2b(v0.y) << 16);
    o.y = f2b(v0.z) | ((unsigned)f2b(v0.w) << 16);
    o.z = f2b(v1.x) | ((unsigned)f2b(v1.y) << 16);
    o.w = f2b(v1.z) | ((unsigned)f2b(v1.w) << 16);
    *(uint4*)&dst[i] = o;
}

__global__ __launch_bounds__(256) void cvt4_kernel(
    const float* __restrict__ a, const float* __restrict__ b,
    const float* __restrict__ c, const float* __restrict__ d,
    ushort_t* __restrict__ oa, ushort_t* __restrict__ ob,
    ushort_t* __restrict__ oc, ushort_t* __restrict__ od)
{
    const float* src = (blockIdx.y == 0) ? a : (blockIdx.y == 1) ? b : (blockIdx.y == 2) ? c : d;
    ushort_t* dst    = (blockIdx.y == 0) ? oa : (blockIdx.y == 1) ? ob : (blockIdx.y == 2) ? oc : od;
    size_t i = ((size_t)blockIdx.x * 256 + threadIdx.x) * 8;
    float4 v0 = *(const float4*)&src[i];
    float4 v1 = *(const float4*)&src[i + 4];
    uint4 o;
    o.x = f2b(v0.x) | ((unsigned)f2b(v0.y) << 16);
    o.y = f2b(v0.z) | ((unsigned)f2b(v0.w) << 16);
    o.z = f2b(v1.x) | ((unsigned)f2b(v1.y) << 16);
    o.w = f2b(v1.z) | ((unsigned)f2b(v1.w) << 16);
    *(uint4*)&dst[i] = o;
}

// ---------------------------------------------------------------------------
// 128x128 bf16 MFMA GEMM mainloop: D = A (MxK) . Bw^T (N x K), both K-contig.
// BK=32, global_load_lds width-16 staging, XOR chunk swizzle (2-way max).
// ---------------------------------------------------------------------------
__device__ __forceinline__ void gemm128_mainloop(
    const ushort_t* __restrict__ A,   // pre-offset to (bm,0), row stride K
    const ushort_t* __restrict__ Bw,  // pre-offset to (bn,0), row stride K
    int K, ushort_t* Asm, ushort_t* Bsm, f32x4 acc[4][4])
{
    const int tid = threadIdx.x;
    const int wave = tid >> 6, lane = tid & 63;
    const int sr = lane >> 2;                        // row within 16-row group
    const int gc = (lane & 3) ^ ((lane >> 3) & 3);   // swizzled global chunk
    const int l15 = lane & 15, q = lane >> 4;
    const int mblk = (wave >> 1) * 64, nblk = (wave & 1) * 64;

    for (int k0 = 0; k0 < K; k0 += 32) {
        #pragma unroll
        for (int o = 0; o < 2; o++) {
            int r0 = (wave * 2 + o) * 16;
            __builtin_amdgcn_global_load_lds(AS1(A + (size_t)(r0 + sr) * K + k0 + gc * 8),
                                             AS3(Asm + r0 * 32), 16, 0, 0);
            __builtin_amdgcn_global_load_lds(AS1(Bw + (size_t)(r0 + sr) * K + k0 + gc * 8),
                                             AS3(Bsm + r0 * 32), 16, 0, 0);
        }
        __syncthreads();

        bf16x8 av[4], bv[4];
        #pragma unroll
        for (int mi = 0; mi < 4; mi++) {
            int r = mblk + mi * 16 + l15;
            av[mi] = *(const bf16x8*)&Asm[r * 32 + (q ^ ((r >> 1) & 3)) * 8];
        }
        #pragma unroll
        for (int ni = 0; ni < 4; ni++) {
            int r = nblk + ni * 16 + l15;
            bv[ni] = *(const bf16x8*)&Bsm[r * 32 + (q ^ ((r >> 1) & 3)) * 8];
        }
        #pragma unroll
        for (int mi = 0; mi < 4; mi++)
            #pragma unroll
            for (int ni = 0; ni < 4; ni++)
                acc[mi][ni] = __builtin_amdgcn_mfma_f32_16x16x32_bf16(av[mi], bv[ni], acc[mi][ni], 0, 0, 0);
        __syncthreads();
    }
}

// Fused Q/K/V projections: z picks which. Output bf16 (B,T,D).
__global__ __launch_bounds__(256) void proj_gemm(
    const ushort_t* __restrict__ qb, const ushort_t* __restrict__ kb, const ushort_t* __restrict__ vb,
    const ushort_t* __restrict__ Wqb, const ushort_t* __restrict__ Wkb, const ushort_t* __restrict__ Wvb,
    const float* __restrict__ bq, const float* __restrict__ bk, const float* __restrict__ bv,
    ushort_t* __restrict__ qh, ushort_t* __restrict__ kh, ushort_t* __restrict__ vh)
{
    __shared__ ushort_t Asm[128 * 32];
    __shared__ ushort_t Bsm[128 * 32];
    const int z = blockIdx.z;
    const ushort_t* A = (z == 0) ? qb : (z == 1) ? kb : vb;
    const ushort_t* W = (z == 0) ? Wqb : (z == 1) ? Wkb : Wvb;
    const float* bias = (z == 0) ? bq : (z == 1) ? bk : bv;
    ushort_t* Y = (z == 0) ? qh : (z == 1) ? kh : vh;

    const int bm = blockIdx.y * 128, bn = blockIdx.x * 128;
    f32x4 acc[4][4];
    #pragma unroll
    for (int i = 0; i < 4; i++)
        #pragma unroll
        for (int j = 0; j < 4; j++) acc[i][j] = (f32x4)(0.f);

    gemm128_mainloop(A + (size_t)bm * DD, W + (size_t)bn * DD, DD, Asm, Bsm, acc);

    const int lane = threadIdx.x & 63, wave = threadIdx.x >> 6;
    const int mblk = (wave >> 1) * 64, nblk = (wave & 1) * 64;
    const int l15 = lane & 15, q = lane >> 4;
    #pragma unroll
    for (int mi = 0; mi < 4; mi++) {
        #pragma unroll
        for (int ni = 0; ni < 4; ni++) {
            int col = bn + nblk + ni * 16 + l15;
            float bcol = bias[col];
            #pragma unroll
            for (int r = 0; r < 4; r++) {
                int row = bm + mblk + mi * 16 + q * 4 + r;
                Y[(size_t)row * DD + col] = f2b(acc[mi][ni][r] + bcol);
            }
        }
    }
}

// Output projection: bf16 in, fp32 out + bias.
__global__ __launch_bounds__(256) void oproj_gemm(
    const ushort_t* __restrict__ A, const ushort_t* __restrict__ W,
    const float* __restrict__ bias, float* __restrict__ Y)
{
    __shared__ ushort_t Asm[128 * 32];
    __shared__ ushort_t Bsm[128 * 32];
    const int bm = blockIdx.y * 128, bn = blockIdx.x * 128;
    f32x4 acc[4][4];
    #pragma unroll
    for (int i = 0; i < 4; i++)
        #pragma unroll
        for (int j = 0; j < 4; j++) acc[i][j] = (f32x4)(0.f);

    gemm128_mainloop(A + (size_t)bm * DD, W + (size_t)bn * DD, DD, Asm, Bsm, acc);

    const int lane = threadIdx.x & 63, wave = threadIdx.x >> 6;
    const int mblk = (wave >> 1) * 64, nblk = (wave & 1) * 64;
    const int l15 = lane & 15, q = lane >> 4;
    #pragma unroll
    for (int mi = 0; mi < 4; mi++) {
        #pragma unroll
        for (int ni = 0; ni < 4; ni++) {
            int col = bn + nblk + ni * 16 + l15;
            float bcol = bias[col];
            #pragma unroll
            for (int r = 0; r < 4; r++) {
                int row = bm + mblk + mi * 16 + q * 4 + r;
                Y[(size_t)row * DD + col] = acc[mi][ni][r] + bcol;
            }
        }
    }
}

// ---------------------------------------------------------------------------
// V transpose: vh (B,S,H,DH) bf16 -> vT (B,H,DH,S) bf16
// ---------------------------------------------------------------------------
__global__ __launch_bounds__(256) void transpose_v(
    const ushort_t* __restrict__ vh, ushort_t* __restrict__ vT)
{
    __shared__ ushort_t Ls[64][72];
    const int s0 = blockIdx.x * 64;
    const int bh = blockIdx.y;
    const int b = bh >> 4, h = bh & 15;
    const int tid = threadIdx.x;
    const int r = tid >> 2, c16 = (tid & 3) * 16;

    const ushort_t* src = &vh[((size_t)(b * SS + s0 + r) * HH + h) * DH + c16];
    uint4 u0 = *(const uint4*)src;
    uint4 u1 = *(const uint4*)(src + 8);
    ushort_t tmp[16];
    *(uint4*)&tmp[0] = u0; *(uint4*)&tmp[8] = u1;
    #pragma unroll
    for (int j = 0; j < 16; j++) Ls[c16 + j][r] = tmp[j];
    __syncthreads();

    const int dh = r;
    uint4 w0 = *(const uint4*)&Ls[dh][c16];
    uint4 w1 = *(const uint4*)&Ls[dh][c16 + 8];
    ushort_t* dst = &vT[((size_t)bh * DH + dh) * SS + s0 + c16];
    *(uint4*)dst = w0;
    *(uint4*)(dst + 8) = w1;
}

// ---------------------------------------------------------------------------
// scores: attn_raw[bh,t,s] = clip(qh.kh/8). 128x128 tile per block, causal
// tiles only. K=64 (one-shot staging, 2 MFMA k-steps).
// ---------------------------------------------------------------------------
__global__ __launch_bounds__(256) void scores_mfma(
    const ushort_t* __restrict__ qh, const ushort_t* __restrict__ kh,
    float* __restrict__ attn)
{
    __shared__ ushort_t Qs[128 * 64];
    __shared__ ushort_t Ks[128 * 64];

    int idx = blockIdx.x, ti = 0;
    while (idx >= ti + 1) { idx -= ti + 1; ti++; }
    const int si = idx;
    const int bh = blockIdx.y;
    const int b = bh >> 4, h = bh & 15;
    const int t0 = ti * 128, s0 = si * 128;

    const int tid = threadIdx.x;
    const int wave = tid >> 6, lane = tid & 63;
    const int sr8 = lane >> 3;                 // 0..7: row within 8-row group
    const int gc8 = (lane & 7) ^ sr8;          // swizzled chunk (8 x 16B per row)

    #pragma unroll
    for (int o = 0; o < 4; o++) {
        int r0 = (wave * 4 + o) * 8;
        int r = r0 + sr8;
        __builtin_amdgcn_global_load_lds(
            AS1(qh + ((size_t)(b * TT + t0 + r) * HH + h) * DH + gc8 * 8),
            AS3(Qs + r0 * 64), 16, 0, 0);
        __builtin_amdgcn_global_load_lds(
            AS1(kh + ((size_t)(b * SS + s0 + r) * HH + h) * DH + gc8 * 8),
            AS3(Ks + r0 * 64), 16, 0, 0);
    }
    __syncthreads();

    const int l15 = lane & 15, q = lane >> 4;
    const int tblk = (wave >> 1) * 64, sblk = (wave & 1) * 64;
    f32x4 acc[4][4];
    #pragma unroll
    for (int i = 0; i < 4; i++)
        #pragma unroll
        for (int j = 0; j < 4; j++) acc[i][j] = (f32x4)(0.f);

    #pragma unroll
    for (int ks = 0; ks < 2; ks++) {
        bf16x8 av[4], bv[4];
        #pragma unroll
        for (int mi = 0; mi < 4; mi++) {
            int r = tblk + mi * 16 + l15;
            av[mi] = *(const bf16x8*)&Qs[r * 64 + ((ks * 4 + q) ^ (r & 7)) * 8];
        }
        #pragma unroll
        for (int ni = 0; ni < 4; ni++) {
            int r = sblk + ni * 16 + l15;
            bv[ni] = *(const bf16x8*)&Ks[r * 64 + ((ks * 4 + q) ^ (r & 7)) * 8];
        }
        #pragma unroll
        for (int mi = 0; mi < 4; mi++)
            #pragma unroll
            for (int ni = 0; ni < 4; ni++)
                acc[mi][ni] = __builtin_amdgcn_mfma_f32_16x16x32_bf16(av[mi], bv[ni], acc[mi][ni], 0, 0, 0);
    }

    #pragma unroll
    for (int mi = 0; mi < 4; mi++) {
        #pragma unroll
        for (int ni = 0; ni < 4; ni++) {
            int scol = s0 + sblk + ni * 16 + l15;
            #pragma unroll
            for (int r = 0; r < 4; r++) {
                int t = t0 + tblk + mi * 16 + q * 4 + r;
                float v = acc[mi][ni][r] * 0.125f;
                v = fminf(fmaxf(v, -80.f), 80.f);
                attn[((size_t)bh * TT + t) * SS + scol] = v;
            }
        }
    }
}

// ---------------------------------------------------------------------------
// softmax + multiplicative tanh bias + renormalize: ONE WAVE PER ROW.
// 4 waves/block, row fully in registers (16 f32/lane), all reductions via
// __shfl_xor (no barriers, no LDS). 8192 blocks -> full occupancy.
// ---------------------------------------------------------------------------
__global__ __launch_bounds__(256) void softmax_bias_wave(
    const float* __restrict__ attn_bias, const float* __restrict__ bias_scale_p,
    float* __restrict__ attn)
{
    const int wave = threadIdx.x >> 6, lane = threadIdx.x & 63;
    const int row = blockIdx.x * 4 + wave;          // (bh*TT + t), 0..32767
    const int t = row & (TT - 1);

    float* prow = attn + (size_t)row * SS;
    const float* brow = attn_bias + (size_t)row * SS;
    const float bscale = bias_scale_p[0];

    const int nc = (t >> 8) + 1;   // # of 256-wide chunks containing s <= t

    // load scores (masked), row-max
    float v[16];
    float m = -INFINITY;
    #pragma unroll
    for (int c = 0; c < 4; c++) {
        const int s0 = c * 256 + lane * 4;
        if (c < nc) {                      // wave-uniform branch
            float4 rv = *(const float4*)&prow[s0];
            v[c * 4 + 0] = (s0     <= t) ? rv.x : -INFINITY;
            v[c * 4 + 1] = (s0 + 1 <= t) ? rv.y : -INFINITY;
            v[c * 4 + 2] = (s0 + 2 <= t) ? rv.z : -INFINITY;
            v[c * 4 + 3] = (s0 + 3 <= t) ? rv.w : -INFINITY;
            m = fmaxf(m, fmaxf(fmaxf(v[c*4], v[c*4+1]), fmaxf(v[c*4+2], v[c*4+3])));
        } else {
            v[c * 4 + 0] = -INFINITY; v[c * 4 + 1] = -INFINITY;
            v[c * 4 + 2] = -INFINITY; v[c * 4 + 3] = -INFINITY;
        }
    }
    #pragma unroll
    for (int off = 1; off < 64; off <<= 1)
        m = fmaxf(m, __shfl_xor(m, off));

    // p = exp(v-m); sc = 1 + bscale*tanh(bias); w = p*sc; accumulate P, W
    float w[16];
    float P = 0.f, Wn = 0.f;
    #pragma unroll
    for (int c = 0; c < 4; c++) {
        const int s0 = c * 256 + lane * 4;
        if (c < nc) {
            float4 bv = *(const float4*)&brow[s0];
            float bx[4] = {bv.x, bv.y, bv.z, bv.w};
            #pragma unroll
            for (int j = 0; j < 4; j++) {
                float vv = v[c * 4 + j];
                float p = (vv > -INFINITY) ? __expf(vv - m) : 0.f;
                float e = __expf(-2.f * fabsf(bx[j]));
                float th = copysignf((1.f - e) / (1.f + e), bx[j]);
                float sc = fmaxf(1.f + bscale * th, 1e-9f);
                float ww = p * sc;
                w[c * 4 + j] = ww;
                P += p; Wn += ww;
            }
        } else {
            w[c * 4 + 0] = 0.f; w[c * 4 + 1] = 0.f;
            w[c * 4 + 2] = 0.f; w[c * 4 + 3] = 0.f;
        }
    }
    #pragma unroll
    for (int off = 1; off < 64; off <<= 1) {
        P  += __shfl_xor(P, off);
        Wn += __shfl_xor(Wn, off);
    }
    // final = p*sc / (Σp*sc + 1e-9*Σp)  ==  softmax*scale renormalized (+eps)
    const float inv = 1.f / (Wn + 1e-9f * P);

    #pragma unroll
    for (int c = 0; c < 4; c++) {
        const int s0 = c * 256 + lane * 4;
        float4 o;
        o.x = w[c * 4 + 0] * inv; o.y = w[c * 4 + 1] * inv;
        o.z = w[c * 4 + 2] * inv; o.w = w[c * 4 + 3] * inv;
        *(float4*)&prow[s0] = o;
    }
}

// ---------------------------------------------------------------------------
// AV: ao[b,t,h*64+dh] = sum_s attn[bh,t,s] * V[s,dh].  64t x 64dh per block.
// A staged fp32->bf16 manually; V staged from vT via global_load_lds.
// attn has exact zeros for s>t, so full diagonal tiles are safe.
// ---------------------------------------------------------------------------
__global__ __launch_bounds__(256) void av_mfma(
    const float* __restrict__ attn, const ushort_t* __restrict__ vT,
    ushort_t* __restrict__ ao)
{
    __shared__ ushort_t Asm[64 * 32];
    __shared__ ushort_t Vsm[64 * 32];

    const int tb = blockIdx.x;
    const int bh = blockIdx.y;
    const int b = bh >> 4, h = bh & 15;
    const int t0 = tb * 64;
    const int nsteps = (tb + 1) * 2;

    const int tid = threadIdx.x;
    const int wave = tid >> 6, lane = tid & 63;
    const int ar = tid >> 2, aq = tid & 3;
    const int aslot = aq ^ ((ar >> 1) & 3);
    const int vsr = lane >> 2;
    const int vgc = (lane & 3) ^ ((lane >> 3) & 3);
    const int l15 = lane & 15, q = lane >> 4;

    f32x4 acc[4];
    #pragma unroll
    for (int i = 0; i < 4; i++) acc[i] = (f32x4)(0.f);

    for (int st = 0; st < nsteps; st++) {
        const int s0 = st * 32;
        {   // stage A (fp32 -> bf16)
            const float* src = &attn[((size_t)bh * TT + t0 + ar) * SS + s0 + aq * 8];
            float4 u0 = *(const float4*)src;
            float4 u1 = *(const float4*)(src + 4);
            uint4 o;
            o.x = f2b(u0.x) | ((unsigned)f2b(u0.y) << 16);
            o.y = f2b(u0.z) | ((unsigned)f2b(u0.w) << 16);
            o.z = f2b(u1.x) | ((unsigned)f2b(u1.y) << 16);
            o.w = f2b(u1.z) | ((unsigned)f2b(u1.w) << 16);
            *(uint4*)&Asm[ar * 32 + aslot * 8] = o;
        }
        {   // stage V rows wave*16..+15
            int r0 = wave * 16;
            __builtin_amdgcn_global_load_lds(
                AS1(vT + ((size_t)bh * DH + r0 + vsr) * SS + s0 + vgc * 8),
                AS3(Vsm + r0 * 32), 16, 0, 0);
        }
        __syncthreads();

        bf16x8 a0, bv[4];
        {
            int r = wave * 16 + l15;
            a0 = *(const bf16x8*)&Asm[r * 32 + (q ^ ((r >> 1) & 3)) * 8];
        }
        #pragma unroll
        for (int ni = 0; ni < 4; ni++) {
            int r = ni * 16 + l15;
            bv[ni] = *(const bf16x8*)&Vsm[r * 32 + (q ^ ((r >> 1) & 3)) * 8];
        }
        #pragma unroll
        for (int ni = 0; ni < 4; ni++)
            acc[ni] = __builtin_amdgcn_mfma_f32_16x16x32_bf16(a0, bv[ni], acc[ni], 0, 0, 0);
        __syncthreads();
    }

    #pragma unroll
    for (int ni = 0; ni < 4; ni++) {
        int dh = ni * 16 + l15;
        #pragma unroll
        for (int r = 0; r < 4; r++) {
            int t = t0 + wave * 16 + q * 4 + r;
            ao[(size_t)(b * TT + t) * DD + h * DH + dh] = f2b(acc[ni][r]);
        }
    }
}

// ---------------------------------------------------------------------------
extern "C" void kernel_launch(void* const* d_in, const int* in_sizes, int n_in,
                              void* d_out, int out_size, void* d_ws, size_t ws_size,
                              hipStream_t stream)
{
    const float* q   = (const float*)d_in[0];
    const float* k   = (const float*)d_in[1];
    const float* v   = (const float*)d_in[2];
    const float* attn_bias = (const float*)d_in[4];
    const float* Wq = (const float*)d_in[5];
    const float* bq = (const float*)d_in[6];
    const float* Wk = (const float*)d_in[7];
    const float* bk = (const float*)d_in[8];
    const float* Wv = (const float*)d_in[9];
    const float* bv = (const float*)d_in[10];
    const float* Wo = (const float*)d_in[11];
    const float* bo = (const float*)d_in[12];
    const float* bscale = (const float*)d_in[13];

    // ws layout (32 MB total, with aliasing):
    char* base = (char*)d_ws;
    ushort_t* qb  = (ushort_t*)(base + (0ull << 20));   // 4 MB, later vT
    ushort_t* kb  = (ushort_t*)(base + (4ull << 20));   // 4 MB, later ao
    ushort_t* vb  = (ushort_t*)(base + (8ull << 20));   // 4 MB
    ushort_t* Wqb = (ushort_t*)(base + (12ull << 20));  // 2 MB
    ushort_t* Wkb = (ushort_t*)(base + (14ull << 20));  // 2 MB
    ushort_t* Wvb = (ushort_t*)(base + (16ull << 20));  // 2 MB
    ushort_t* Wob = (ushort_t*)(base + (18ull << 20));  // 2 MB
    ushort_t* qhb = (ushort_t*)(base + (20ull << 20));  // 4 MB
    ushort_t* khb = (ushort_t*)(base + (24ull << 20));  // 4 MB
    ushort_t* vhb = (ushort_t*)(base + (28ull << 20));  // 4 MB
    ushort_t* vT  = qb;   // alias: qb dead after proj_gemm
    ushort_t* aob = kb;   // alias: kb dead after proj_gemm

    float* out  = (float*)d_out;
    float* attn = out + (size_t)BB * TT * DD;

    cvt3_kernel<<<dim3(1024, 3), 256, 0, stream>>>(q, k, v, qb, kb, vb);
    cvt4_kernel<<<dim3(512, 4), 256, 0, stream>>>(Wq, Wk, Wv, Wo, Wqb, Wkb, Wvb, Wob);
    proj_gemm<<<dim3(8, 16, 3), 256, 0, stream>>>(qb, kb, vb, Wqb, Wkb, Wvb,
                                                  bq, bk, bv, qhb, khb, vhb);
    transpose_v<<<dim3(16, 32), 256, 0, stream>>>(vhb, vT);
    scores_mfma<<<dim3(36, 32), 256, 0, stream>>>(qhb, khb, attn);
    softmax_bias_wave<<<dim3(8192), 256, 0, stream>>>(attn_bias, bscale, attn);
    av_mfma<<<dim3(16, 32), 256, 0, stream>>>(attn, vT, aob);
    oproj_gemm<<<dim3(8, 16), 256, 0, stream>>>(aob, Wob, bo, out);
}

// Round 3
// 374.830 us; speedup vs baseline: 1.4833x; 1.0001x over previous
//
#include <hip/hip_runtime.h>
#include <hip/hip_bf16.h>
#include <math.h>

#define BB 2
#define TT 1024
#define SS 1024
#define DD 1024
#define HH 16
#define DH 64

typedef __attribute__((ext_vector_type(8))) short bf16x8;
typedef __attribute__((ext_vector_type(4))) float f32x4;
typedef unsigned short ushort_t;

#define AS3(p) ((__attribute__((address_space(3))) unsigned int*)(p))
#define AS1(p) ((const __attribute__((address_space(1))) unsigned int*)(p))

__device__ __forceinline__ unsigned short f2b(float f) {
    union { float f; unsigned u; } x; x.f = f;
    unsigned r = x.u + 0x7FFFu + ((x.u >> 16) & 1u);
    return (unsigned short)(r >> 16);
}

// pack 8 f32 -> bf16x8 via v_cvt_pk_bf16_f32 (RNE)
__device__ __forceinline__ bf16x8 pack_bf16x8(float4 a, float4 b) {
    union { unsigned u[4]; bf16x8 v; } r;
    asm("v_cvt_pk_bf16_f32 %0, %1, %2" : "=v"(r.u[0]) : "v"(a.x), "v"(a.y));
    asm("v_cvt_pk_bf16_f32 %0, %1, %2" : "=v"(r.u[1]) : "v"(a.z), "v"(a.w));
    asm("v_cvt_pk_bf16_f32 %0, %1, %2" : "=v"(r.u[2]) : "v"(b.x), "v"(b.y));
    asm("v_cvt_pk_bf16_f32 %0, %1, %2" : "=v"(r.u[3]) : "v"(b.z), "v"(b.w));
    return r.v;
}

// ---------------------------------------------------------------------------
// fp32 -> bf16 conversion kernels
// ---------------------------------------------------------------------------
__global__ __launch_bounds__(256) void cvt3_kernel(
    const float* __restrict__ a, const float* __restrict__ b, const float* __restrict__ c,
    ushort_t* __restrict__ oa, ushort_t* __restrict__ ob, ushort_t* __restrict__ oc)
{
    const float* src = (blockIdx.y == 0) ? a : (blockIdx.y == 1) ? b : c;
    ushort_t* dst    = (blockIdx.y == 0) ? oa : (blockIdx.y == 1) ? ob : oc;
    size_t i = ((size_t)blockIdx.x * 256 + threadIdx.x) * 8;
    float4 v0 = *(const float4*)&src[i];
    float4 v1 = *(const float4*)&src[i + 4];
    uint4 o;
    o.x = f2b(v0.x) | ((unsigned)f2b(v0.y) << 16);
    o.y = f2b(v0.z) | ((unsigned)f2b(v0.w) << 16);
    o.z = f2b(v1.x) | ((unsigned)f2b(v1.y) << 16);
    o.w = f2b(v1.z) | ((unsigned)f2b(v1.w) << 16);
    *(uint4*)&dst[i] = o;
}

__global__ __launch_bounds__(256) void cvt4_kernel(
    const float* __restrict__ a, const float* __restrict__ b,
    const float* __restrict__ c, const float* __restrict__ d,
    ushort_t* __restrict__ oa, ushort_t* __restrict__ ob,
    ushort_t* __restrict__ oc, ushort_t* __restrict__ od)
{
    const float* src = (blockIdx.y == 0) ? a : (blockIdx.y == 1) ? b : (blockIdx.y == 2) ? c : d;
    ushort_t* dst    = (blockIdx.y == 0) ? oa : (blockIdx.y == 1) ? ob : (blockIdx.y == 2) ? oc : od;
    size_t i = ((size_t)blockIdx.x * 256 + threadIdx.x) * 8;
    float4 v0 = *(const float4*)&src[i];
    float4 v1 = *(const float4*)&src[i + 4];
    uint4 o;
    o.x = f2b(v0.x) | ((unsigned)f2b(v0.y) << 16);
    o.y = f2b(v0.z) | ((unsigned)f2b(v0.w) << 16);
    o.z = f2b(v1.x) | ((unsigned)f2b(v1.y) << 16);
    o.w = f2b(v1.z) | ((unsigned)f2b(v1.w) << 16);
    *(uint4*)&dst[i] = o;
}

// ---------------------------------------------------------------------------
// 128x128 bf16 MFMA GEMM mainloop: D = A (MxK) . Bw^T (N x K), both K-contig.
// BK=64: 2 barriers per 32 MFMA (halved vs BK=32), scores-style 8-chunk XOR
// swizzle (2-way bank conflict max on ds_read_b128).
// ---------------------------------------------------------------------------
__device__ __forceinline__ void gemm128_mainloop(
    const ushort_t* __restrict__ A,   // pre-offset to (bm,0), row stride K
    const ushort_t* __restrict__ Bw,  // pre-offset to (bn,0), row stride K
    int K, ushort_t* Asm, ushort_t* Bsm, f32x4 acc[4][4])
{
    const int tid = threadIdx.x;
    const int wave = tid >> 6, lane = tid & 63;
    const int sr8 = lane >> 3;                 // row within 8-row group
    const int gc8 = (lane & 7) ^ sr8;          // swizzled global chunk (8x16B/row)
    const int l15 = lane & 15, q = lane >> 4;
    const int mblk = (wave >> 1) * 64, nblk = (wave & 1) * 64;

    for (int k0 = 0; k0 < K; k0 += 64) {
        #pragma unroll
        for (int o = 0; o < 4; o++) {
            int r0 = wave * 32 + o * 8;
            __builtin_amdgcn_global_load_lds(AS1(A + (size_t)(r0 + sr8) * K + k0 + gc8 * 8),
                                             AS3(Asm + r0 * 64), 16, 0, 0);
            __builtin_amdgcn_global_load_lds(AS1(Bw + (size_t)(r0 + sr8) * K + k0 + gc8 * 8),
                                             AS3(Bsm + r0 * 64), 16, 0, 0);
        }
        __syncthreads();

        #pragma unroll
        for (int ks = 0; ks < 2; ks++) {
            bf16x8 av[4], bv[4];
            #pragma unroll
            for (int mi = 0; mi < 4; mi++) {
                int r = mblk + mi * 16 + l15;
                av[mi] = *(const bf16x8*)&Asm[r * 64 + ((ks * 4 + q) ^ (r & 7)) * 8];
            }
            #pragma unroll
            for (int ni = 0; ni < 4; ni++) {
                int r = nblk + ni * 16 + l15;
                bv[ni] = *(const bf16x8*)&Bsm[r * 64 + ((ks * 4 + q) ^ (r & 7)) * 8];
            }
            #pragma unroll
            for (int mi = 0; mi < 4; mi++)
                #pragma unroll
                for (int ni = 0; ni < 4; ni++)
                    acc[mi][ni] = __builtin_amdgcn_mfma_f32_16x16x32_bf16(av[mi], bv[ni], acc[mi][ni], 0, 0, 0);
        }
        __syncthreads();
    }
}

// Fused Q/K/V projections: z picks which. Output bf16 (B,T,D).
__global__ __launch_bounds__(256) void proj_gemm(
    const ushort_t* __restrict__ qb, const ushort_t* __restrict__ kb, const ushort_t* __restrict__ vb,
    const ushort_t* __restrict__ Wqb, const ushort_t* __restrict__ Wkb, const ushort_t* __restrict__ Wvb,
    const float* __restrict__ bq, const float* __restrict__ bk, const float* __restrict__ bv,
    ushort_t* __restrict__ qh, ushort_t* __restrict__ kh, ushort_t* __restrict__ vh)
{
    __shared__ ushort_t Asm[128 * 64];
    __shared__ ushort_t Bsm[128 * 64];
    const int z = blockIdx.z;
    const ushort_t* A = (z == 0) ? qb : (z == 1) ? kb : vb;
    const ushort_t* W = (z == 0) ? Wqb : (z == 1) ? Wkb : Wvb;
    const float* bias = (z == 0) ? bq : (z == 1) ? bk : bv;
    ushort_t* Y = (z == 0) ? qh : (z == 1) ? kh : vh;

    const int bm = blockIdx.y * 128, bn = blockIdx.x * 128;
    f32x4 acc[4][4];
    #pragma unroll
    for (int i = 0; i < 4; i++)
        #pragma unroll
        for (int j = 0; j < 4; j++) acc[i][j] = (f32x4)(0.f);

    gemm128_mainloop(A + (size_t)bm * DD, W + (size_t)bn * DD, DD, Asm, Bsm, acc);

    const int lane = threadIdx.x & 63, wave = threadIdx.x >> 6;
    const int mblk = (wave >> 1) * 64, nblk = (wave & 1) * 64;
    const int l15 = lane & 15, q = lane >> 4;
    #pragma unroll
    for (int mi = 0; mi < 4; mi++) {
        #pragma unroll
        for (int ni = 0; ni < 4; ni++) {
            int col = bn + nblk + ni * 16 + l15;
            float bcol = bias[col];
            #pragma unroll
            for (int r = 0; r < 4; r++) {
                int row = bm + mblk + mi * 16 + q * 4 + r;
                Y[(size_t)row * DD + col] = f2b(acc[mi][ni][r] + bcol);
            }
        }
    }
}

// Output projection: bf16 in, fp32 out + bias.
__global__ __launch_bounds__(256) void oproj_gemm(
    const ushort_t* __restrict__ A, const ushort_t* __restrict__ W,
    const float* __restrict__ bias, float* __restrict__ Y)
{
    __shared__ ushort_t Asm[128 * 64];
    __shared__ ushort_t Bsm[128 * 64];
    const int bm = blockIdx.y * 128, bn = blockIdx.x * 128;
    f32x4 acc[4][4];
    #pragma unroll
    for (int i = 0; i < 4; i++)
        #pragma unroll
        for (int j = 0; j < 4; j++) acc[i][j] = (f32x4)(0.f);

    gemm128_mainloop(A + (size_t)bm * DD, W + (size_t)bn * DD, DD, Asm, Bsm, acc);

    const int lane = threadIdx.x & 63, wave = threadIdx.x >> 6;
    const int mblk = (wave >> 1) * 64, nblk = (wave & 1) * 64;
    const int l15 = lane & 15, q = lane >> 4;
    #pragma unroll
    for (int mi = 0; mi < 4; mi++) {
        #pragma unroll
        for (int ni = 0; ni < 4; ni++) {
            int col = bn + nblk + ni * 16 + l15;
            float bcol = bias[col];
            #pragma unroll
            for (int r = 0; r < 4; r++) {
                int row = bm + mblk + mi * 16 + q * 4 + r;
                Y[(size_t)row * DD + col] = acc[mi][ni][r] + bcol;
            }
        }
    }
}

// ---------------------------------------------------------------------------
// V transpose: vh (B,S,H,DH) bf16 -> vT (B,H,DH,S) bf16
// ---------------------------------------------------------------------------
__global__ __launch_bounds__(256) void transpose_v(
    const ushort_t* __restrict__ vh, ushort_t* __restrict__ vT)
{
    __shared__ ushort_t Ls[64][72];
    const int s0 = blockIdx.x * 64;
    const int bh = blockIdx.y;
    const int b = bh >> 4, h = bh & 15;
    const int tid = threadIdx.x;
    const int r = tid >> 2, c16 = (tid & 3) * 16;

    const ushort_t* src = &vh[((size_t)(b * SS + s0 + r) * HH + h) * DH + c16];
    uint4 u0 = *(const uint4*)src;
    uint4 u1 = *(const uint4*)(src + 8);
    ushort_t tmp[16];
    *(uint4*)&tmp[0] = u0; *(uint4*)&tmp[8] = u1;
    #pragma unroll
    for (int j = 0; j < 16; j++) Ls[c16 + j][r] = tmp[j];
    __syncthreads();

    const int dh = r;
    uint4 w0 = *(const uint4*)&Ls[dh][c16];
    uint4 w1 = *(const uint4*)&Ls[dh][c16 + 8];
    ushort_t* dst = &vT[((size_t)bh * DH + dh) * SS + s0 + c16];
    *(uint4*)dst = w0;
    *(uint4*)(dst + 8) = w1;
}

// ---------------------------------------------------------------------------
// scores: attn_raw[bh,t,s] = clip(qh.kh/8). 128x128 tile per block, causal
// tiles only. K=64 (one-shot staging, 2 MFMA k-steps).
// ---------------------------------------------------------------------------
__global__ __launch_bounds__(256) void scores_mfma(
    const ushort_t* __restrict__ qh, const ushort_t* __restrict__ kh,
    float* __restrict__ attn)
{
    __shared__ ushort_t Qs[128 * 64];
    __shared__ ushort_t Ks[128 * 64];

    int idx = blockIdx.x, ti = 0;
    while (idx >= ti + 1) { idx -= ti + 1; ti++; }
    const int si = idx;
    const int bh = blockIdx.y;
    const int b = bh >> 4, h = bh & 15;
    const int t0 = ti * 128, s0 = si * 128;

    const int tid = threadIdx.x;
    const int wave = tid >> 6, lane = tid & 63;
    const int sr8 = lane >> 3;                 // 0..7: row within 8-row group
    const int gc8 = (lane & 7) ^ sr8;          // swizzled chunk (8 x 16B per row)

    #pragma unroll
    for (int o = 0; o < 4; o++) {
        int r0 = (wave * 4 + o) * 8;
        int r = r0 + sr8;
        __builtin_amdgcn_global_load_lds(
            AS1(qh + ((size_t)(b * TT + t0 + r) * HH + h) * DH + gc8 * 8),
            AS3(Qs + r0 * 64), 16, 0, 0);
        __builtin_amdgcn_global_load_lds(
            AS1(kh + ((size_t)(b * SS + s0 + r) * HH + h) * DH + gc8 * 8),
            AS3(Ks + r0 * 64), 16, 0, 0);
    }
    __syncthreads();

    const int l15 = lane & 15, q = lane >> 4;
    const int tblk = (wave >> 1) * 64, sblk = (wave & 1) * 64;
    f32x4 acc[4][4];
    #pragma unroll
    for (int i = 0; i < 4; i++)
        #pragma unroll
        for (int j = 0; j < 4; j++) acc[i][j] = (f32x4)(0.f);

    #pragma unroll
    for (int ks = 0; ks < 2; ks++) {
        bf16x8 av[4], bv[4];
        #pragma unroll
        for (int mi = 0; mi < 4; mi++) {
            int r = tblk + mi * 16 + l15;
            av[mi] = *(const bf16x8*)&Qs[r * 64 + ((ks * 4 + q) ^ (r & 7)) * 8];
        }
        #pragma unroll
        for (int ni = 0; ni < 4; ni++) {
            int r = sblk + ni * 16 + l15;
            bv[ni] = *(const bf16x8*)&Ks[r * 64 + ((ks * 4 + q) ^ (r & 7)) * 8];
        }
        #pragma unroll
        for (int mi = 0; mi < 4; mi++)
            #pragma unroll
            for (int ni = 0; ni < 4; ni++)
                acc[mi][ni] = __builtin_amdgcn_mfma_f32_16x16x32_bf16(av[mi], bv[ni], acc[mi][ni], 0, 0, 0);
    }

    #pragma unroll
    for (int mi = 0; mi < 4; mi++) {
        #pragma unroll
        for (int ni = 0; ni < 4; ni++) {
            int scol = s0 + sblk + ni * 16 + l15;
            #pragma unroll
            for (int r = 0; r < 4; r++) {
                int t = t0 + tblk + mi * 16 + q * 4 + r;
                float v = acc[mi][ni][r] * 0.125f;
                v = fminf(fmaxf(v, -80.f), 80.f);
                attn[((size_t)bh * TT + t) * SS + scol] = v;
            }
        }
    }
}

// ---------------------------------------------------------------------------
// softmax + multiplicative tanh bias + renormalize: ONE WAVE PER ROW.
// 4 waves/block, row fully in registers (16 f32/lane), all reductions via
// __shfl_xor (no barriers, no LDS). 8192 blocks -> full occupancy.
// ---------------------------------------------------------------------------
__global__ __launch_bounds__(256) void softmax_bias_wave(
    const float* __restrict__ attn_bias, const float* __restrict__ bias_scale_p,
    float* __restrict__ attn)
{
    const int wave = threadIdx.x >> 6, lane = threadIdx.x & 63;
    const int row = blockIdx.x * 4 + wave;          // (bh*TT + t), 0..32767
    const int t = row & (TT - 1);

    float* prow = attn + (size_t)row * SS;
    const float* brow = attn_bias + (size_t)row * SS;
    const float bscale = bias_scale_p[0];

    const int nc = (t >> 8) + 1;   // # of 256-wide chunks containing s <= t

    // load scores (masked), row-max
    float v[16];
    float m = -INFINITY;
    #pragma unroll
    for (int c = 0; c < 4; c++) {
        const int s0 = c * 256 + lane * 4;
        if (c < nc) {                      // wave-uniform branch
            float4 rv = *(const float4*)&prow[s0];
            v[c * 4 + 0] = (s0     <= t) ? rv.x : -INFINITY;
            v[c * 4 + 1] = (s0 + 1 <= t) ? rv.y : -INFINITY;
            v[c * 4 + 2] = (s0 + 2 <= t) ? rv.z : -INFINITY;
            v[c * 4 + 3] = (s0 + 3 <= t) ? rv.w : -INFINITY;
            m = fmaxf(m, fmaxf(fmaxf(v[c*4], v[c*4+1]), fmaxf(v[c*4+2], v[c*4+3])));
        } else {
            v[c * 4 + 0] = -INFINITY; v[c * 4 + 1] = -INFINITY;
            v[c * 4 + 2] = -INFINITY; v[c * 4 + 3] = -INFINITY;
        }
    }
    #pragma unroll
    for (int off = 1; off < 64; off <<= 1)
        m = fmaxf(m, __shfl_xor(m, off));

    // p = exp(v-m); sc = 1 + bscale*tanh(bias); w = p*sc; accumulate P, W
    float w[16];
    float P = 0.f, Wn = 0.f;
    #pragma unroll
    for (int c = 0; c < 4; c++) {
        const int s0 = c * 256 + lane * 4;
        if (c < nc) {
            float4 bv = *(const float4*)&brow[s0];
            float bx[4] = {bv.x, bv.y, bv.z, bv.w};
            #pragma unroll
            for (int j = 0; j < 4; j++) {
                float vv = v[c * 4 + j];
                float p = (vv > -INFINITY) ? __expf(vv - m) : 0.f;
                float e = __expf(-2.f * fabsf(bx[j]));
                float th = copysignf((1.f - e) / (1.f + e), bx[j]);
                float sc = fmaxf(1.f + bscale * th, 1e-9f);
                float ww = p * sc;
                w[c * 4 + j] = ww;
                P += p; Wn += ww;
            }
        } else {
            w[c * 4 + 0] = 0.f; w[c * 4 + 1] = 0.f;
            w[c * 4 + 2] = 0.f; w[c * 4 + 3] = 0.f;
        }
    }
    #pragma unroll
    for (int off = 1; off < 64; off <<= 1) {
        P  += __shfl_xor(P, off);
        Wn += __shfl_xor(Wn, off);
    }
    // final = p*sc / (Σp*sc + 1e-9*Σp)  ==  softmax*scale renormalized (+eps)
    const float inv = 1.f / (Wn + 1e-9f * P);

    #pragma unroll
    for (int c = 0; c < 4; c++) {
        const int s0 = c * 256 + lane * 4;
        float4 o;
        o.x = w[c * 4 + 0] * inv; o.y = w[c * 4 + 1] * inv;
        o.z = w[c * 4 + 2] * inv; o.w = w[c * 4 + 3] * inv;
        *(float4*)&prow[s0] = o;
    }
}

// ---------------------------------------------------------------------------
// AV: ao[b,t,h*64+dh] = sum_s attn[bh,t,s] * V[s,dh].  64t x 64dh per block.
// 64-wide s-steps. A-fragments read DIRECTLY from global fp32 (MFMA A-layout
// = 2x float4 per lane) + v_cvt_pk_bf16_f32; V double-buffered in LDS via
// global_load_lds (T3-minimal: stage(t+1) -> compute(t) -> one barrier).
// attn has exact zeros for s>t, so full diagonal tiles are safe.
// ---------------------------------------------------------------------------
__global__ __launch_bounds__(256) void av_mfma(
    const float* __restrict__ attn, const ushort_t* __restrict__ vT,
    ushort_t* __restrict__ ao)
{
    __shared__ ushort_t Vsm[2][64 * 64];   // 2 x 8 KB, XOR-chunk swizzled

    const int tb = (int)gridDim.x - 1 - (int)blockIdx.x;   // heavy blocks first
    const int bh = blockIdx.y;
    const int b = bh >> 4, h = bh & 15;
    const int t0 = tb * 64;
    const int nsteps = tb + 1;             // 64-wide s-steps covering s <= t

    const int tid = threadIdx.x;
    const int wave = tid >> 6, lane = tid & 63;
    const int sr8 = lane >> 3, gc8 = (lane & 7) ^ sr8;
    const int l15 = lane & 15, q = lane >> 4;

    // this lane's A-row pointer (t-row = t0 + wave*16 + l15), k-offset q*8
    const float* arow = attn + ((size_t)bh * TT + t0 + wave * 16 + l15) * SS + q * 8;
    const ushort_t* vbase = vT + (size_t)bh * DH * SS;

    f32x4 acc[4];
    #pragma unroll
    for (int i = 0; i < 4; i++) acc[i] = (f32x4)(0.f);

#define STAGE_V(sidx, buf) do {                                               \
        int s0_ = (sidx) * 64;                                                \
        _Pragma("unroll")                                                     \
        for (int o = 0; o < 2; o++) {                                         \
            int r0 = wave * 16 + o * 8;                                       \
            __builtin_amdgcn_global_load_lds(                                 \
                AS1(vbase + (size_t)(r0 + sr8) * SS + s0_ + gc8 * 8),         \
                AS3(&Vsm[buf][r0 * 64]), 16, 0, 0);                           \
        } } while (0)

#define LOAD_A(sidx, dst) do {                                                \
        const float* p_ = arow + (sidx) * 64;                                 \
        dst[0] = *(const float4*)(p_);                                        \
        dst[1] = *(const float4*)(p_ + 4);                                    \
        dst[2] = *(const float4*)(p_ + 32);                                   \
        dst[3] = *(const float4*)(p_ + 36); } while (0)

#define COMPUTE(buf, ax) do {                                                 \
        bf16x8 af0 = pack_bf16x8(ax[0], ax[1]);                               \
        bf16x8 af1 = pack_bf16x8(ax[2], ax[3]);                               \
        _Pragma("unroll")                                                     \
        for (int ni = 0; ni < 4; ni++) {                                      \
            int rv = ni * 16 + l15;                                           \
            bf16x8 b0 = *(const bf16x8*)&Vsm[buf][rv * 64 + ((q) ^ (rv & 7)) * 8];       \
            bf16x8 b1 = *(const bf16x8*)&Vsm[buf][rv * 64 + ((4 + q) ^ (rv & 7)) * 8];   \
            acc[ni] = __builtin_amdgcn_mfma_f32_16x16x32_bf16(af0, b0, acc[ni], 0, 0, 0);\
            acc[ni] = __builtin_amdgcn_mfma_f32_16x16x32_bf16(af1, b1, acc[ni], 0, 0, 0);\
        } } while (0)

    float4 aA[4], aB[4];
    STAGE_V(0, 0);
    LOAD_A(0, aA);
    __syncthreads();

    int st = 0;
    while (true) {
        if (st + 1 < nsteps) { STAGE_V(st + 1, 1); LOAD_A(st + 1, aB); }
        COMPUTE(0, aA);
        __syncthreads();
        if (++st == nsteps) break;
        if (st + 1 < nsteps) { STAGE_V(st + 1, 0); LOAD_A(st + 1, aA); }
        COMPUTE(1, aB);
        __syncthreads();
        if (++st == nsteps) break;
    }

#undef STAGE_V
#undef LOAD_A
#undef COMPUTE

    #pragma unroll
    for (int ni = 0; ni < 4; ni++) {
        int dh = ni * 16 + l15;
        #pragma unroll
        for (int r = 0; r < 4; r++) {
            int t = t0 + wave * 16 + q * 4 + r;
            ao[(size_t)(b * TT + t) * DD + h * DH + dh] = f2b(acc[ni][r]);
        }
    }
}

// ---------------------------------------------------------------------------
extern "C" void kernel_launch(void* const* d_in, const int* in_sizes, int n_in,
                              void* d_out, int out_size, void* d_ws, size_t ws_size,
                              hipStream_t stream)
{
    const float* q   = (const float*)d_in[0];
    const float* k   = (const float*)d_in[1];
    const float* v   = (const float*)d_in[2];
    const float* attn_bias = (const float*)d_in[4];
    const float* Wq = (const float*)d_in[5];
    const float* bq = (const float*)d_in[6];
    const float* Wk = (const float*)d_in[7];
    const float* bk = (const float*)d_in[8];
    const float* Wv = (const float*)d_in[9];
    const float* bv = (const float*)d_in[10];
    const float* Wo = (const float*)d_in[11];
    const float* bo = (const float*)d_in[12];
    const float* bscale = (const float*)d_in[13];

    // ws layout (32 MB total, with aliasing):
    char* base = (char*)d_ws;
    ushort_t* qb  = (ushort_t*)(base + (0ull << 20));   // 4 MB, later vT
    ushort_t* kb  = (ushort_t*)(base + (4ull << 20));   // 4 MB, later ao
    ushort_t* vb  = (ushort_t*)(base + (8ull << 20));   // 4 MB
    ushort_t* Wqb = (ushort_t*)(base + (12ull << 20));  // 2 MB
    ushort_t* Wkb = (ushort_t*)(base + (14ull << 20));  // 2 MB
    ushort_t* Wvb = (ushort_t*)(base + (16ull << 20));  // 2 MB
    ushort_t* Wob = (ushort_t*)(base + (18ull << 20));  // 2 MB
    ushort_t* qhb = (ushort_t*)(base + (20ull << 20));  // 4 MB
    ushort_t* khb = (ushort_t*)(base + (24ull << 20));  // 4 MB
    ushort_t* vhb = (ushort_t*)(base + (28ull << 20));  // 4 MB
    ushort_t* vT  = qb;   // alias: qb dead after proj_gemm
    ushort_t* aob = kb;   // alias: kb dead after proj_gemm

    float* out  = (float*)d_out;
    float* attn = out + (size_t)BB * TT * DD;

    cvt3_kernel<<<dim3(1024, 3), 256, 0, stream>>>(q, k, v, qb, kb, vb);
    cvt4_kernel<<<dim3(512, 4), 256, 0, stream>>>(Wq, Wk, Wv, Wo, Wqb, Wkb, Wvb, Wob);
    proj_gemm<<<dim3(8, 16, 3), 256, 0, stream>>>(qb, kb, vb, Wqb, Wkb, Wvb,
                                                  bq, bk, bv, qhb, khb, vhb);
    transpose_v<<<dim3(16, 32), 256, 0, stream>>>(vhb, vT);
    scores_mfma<<<dim3(36, 32), 256, 0, stream>>>(qhb, khb, attn);
    softmax_bias_wave<<<dim3(8192), 256, 0, stream>>>(attn_bias, bscale, attn);
    av_mfma<<<dim3(16, 32), 256, 0, stream>>>(attn, vT, aob);
    oproj_gemm<<<dim3(8, 16), 256, 0, stream>>>(aob, Wob, bo, out);
}

// Round 4
// 367.433 us; speedup vs baseline: 1.5131x; 1.0201x over previous
//
#include <hip/hip_runtime.h>
#include <hip/hip_bf16.h>
#include <math.h>

#define BB 2
#define TT 1024
#define SS 1024
#define DD 1024
#define HH 16
#define DH 64

typedef __attribute__((ext_vector_type(8))) short bf16x8;
typedef __attribute__((ext_vector_type(4))) float f32x4;
typedef unsigned short ushort_t;

#define AS3(p) ((__attribute__((address_space(3))) unsigned int*)(p))
#define AS1(p) ((const __attribute__((address_space(1))) unsigned int*)(p))

__device__ __forceinline__ unsigned short f2b(float f) {
    union { float f; unsigned u; } x; x.f = f;
    unsigned r = x.u + 0x7FFFu + ((x.u >> 16) & 1u);
    return (unsigned short)(r >> 16);
}

// pack 8 f32 -> bf16x8 via v_cvt_pk_bf16_f32 (RNE)
__device__ __forceinline__ bf16x8 pack_bf16x8(float4 a, float4 b) {
    union { unsigned u[4]; bf16x8 v; } r;
    asm("v_cvt_pk_bf16_f32 %0, %1, %2" : "=v"(r.u[0]) : "v"(a.x), "v"(a.y));
    asm("v_cvt_pk_bf16_f32 %0, %1, %2" : "=v"(r.u[1]) : "v"(a.z), "v"(a.w));
    asm("v_cvt_pk_bf16_f32 %0, %1, %2" : "=v"(r.u[2]) : "v"(b.x), "v"(b.y));
    asm("v_cvt_pk_bf16_f32 %0, %1, %2" : "=v"(r.u[3]) : "v"(b.z), "v"(b.w));
    return r.v;
}

// ---------------------------------------------------------------------------
// fp32 -> bf16 conversion: ONE kernel for all 7 tensors.
// y<3: q/k/v (2M elems, 1024 blocks). y>=3: Wq/Wk/Wv/Wo (1M elems, 512 blocks).
// ---------------------------------------------------------------------------
__global__ __launch_bounds__(256) void cvt_all(
    const float* __restrict__ q, const float* __restrict__ k, const float* __restrict__ v,
    const float* __restrict__ Wq, const float* __restrict__ Wk,
    const float* __restrict__ Wv, const float* __restrict__ Wo,
    ushort_t* __restrict__ oq, ushort_t* __restrict__ ok, ushort_t* __restrict__ ov,
    ushort_t* __restrict__ oWq, ushort_t* __restrict__ oWk,
    ushort_t* __restrict__ oWv, ushort_t* __restrict__ oWo)
{
    const int y = blockIdx.y;
    if (y >= 3 && blockIdx.x >= 512) return;
    const float* src =
        (y == 0) ? q : (y == 1) ? k : (y == 2) ? v :
        (y == 3) ? Wq : (y == 4) ? Wk : (y == 5) ? Wv : Wo;
    ushort_t* dst =
        (y == 0) ? oq : (y == 1) ? ok : (y == 2) ? ov :
        (y == 3) ? oWq : (y == 4) ? oWk : (y == 5) ? oWv : oWo;
    size_t i = ((size_t)blockIdx.x * 256 + threadIdx.x) * 8;
    float4 v0 = *(const float4*)&src[i];
    float4 v1 = *(const float4*)&src[i + 4];
    uint4 o;
    o.x = f2b(v0.x) | ((unsigned)f2b(v0.y) << 16);
    o.y = f2b(v0.z) | ((unsigned)f2b(v0.w) << 16);
    o.z = f2b(v1.x) | ((unsigned)f2b(v1.y) << 16);
    o.w = f2b(v1.z) | ((unsigned)f2b(v1.w) << 16);
    *(uint4*)&dst[i] = o;
}

// ---------------------------------------------------------------------------
// 128x128 bf16 MFMA GEMM mainloop: D = A (MxK) . Bw^T (N x K), both K-contig.
// BK=32, PING-PONG double-buffer: STAGE(k+1,buf^1) -> COMPUTE(buf) -> one
// barrier per step. Stage latency hides under 16 MFMA + 8 ds_read_b128.
// LDS 32 KB total (occupancy preserved at ~3 blocks/CU).
// ---------------------------------------------------------------------------
__device__ __forceinline__ void gemm128_mainloop(
    const ushort_t* __restrict__ A,   // pre-offset to (bm,0), row stride K
    const ushort_t* __restrict__ Bw,  // pre-offset to (bn,0), row stride K
    int K, ushort_t (*Asm)[128 * 32], ushort_t (*Bsm)[128 * 32],
    f32x4 acc[4][4])
{
    const int tid = threadIdx.x;
    const int wave = tid >> 6, lane = tid & 63;
    const int sr = lane >> 2;                        // row within 16-row group
    const int gc = (lane & 3) ^ ((lane >> 3) & 3);   // swizzled global chunk
    const int l15 = lane & 15, q = lane >> 4;
    const int mblk = (wave >> 1) * 64, nblk = (wave & 1) * 64;

#define G128_STAGE(k0_, b_) do {                                               \
        _Pragma("unroll")                                                      \
        for (int o = 0; o < 2; o++) {                                          \
            int r0 = (wave * 2 + o) * 16;                                      \
            __builtin_amdgcn_global_load_lds(                                  \
                AS1(A + (size_t)(r0 + sr) * K + (k0_) + gc * 8),               \
                AS3(Asm[b_] + r0 * 32), 16, 0, 0);                             \
            __builtin_amdgcn_global_load_lds(                                  \
                AS1(Bw + (size_t)(r0 + sr) * K + (k0_) + gc * 8),              \
                AS3(Bsm[b_] + r0 * 32), 16, 0, 0);                             \
        } } while (0)

#define G128_COMPUTE(b_) do {                                                  \
        bf16x8 av[4], bv[4];                                                   \
        _Pragma("unroll")                                                      \
        for (int mi = 0; mi < 4; mi++) {                                       \
            int r = mblk + mi * 16 + l15;                                      \
            av[mi] = *(const bf16x8*)&Asm[b_][r * 32 + (q ^ ((r >> 1) & 3)) * 8]; \
        }                                                                      \
        _Pragma("unroll")                                                      \
        for (int ni = 0; ni < 4; ni++) {                                       \
            int r = nblk + ni * 16 + l15;                                      \
            bv[ni] = *(const bf16x8*)&Bsm[b_][r * 32 + (q ^ ((r >> 1) & 3)) * 8]; \
        }                                                                      \
        _Pragma("unroll")                                                      \
        for (int mi = 0; mi < 4; mi++)                                         \
            _Pragma("unroll")                                                  \
            for (int ni = 0; ni < 4; ni++)                                     \
                acc[mi][ni] = __builtin_amdgcn_mfma_f32_16x16x32_bf16(         \
                    av[mi], bv[ni], acc[mi][ni], 0, 0, 0);                     \
        } while (0)

    G128_STAGE(0, 0);
    __syncthreads();                 // drain stage(0)

    int buf = 0;
    for (int k0 = 0; k0 < K; k0 += 32) {
        if (k0 + 32 < K) G128_STAGE(k0 + 32, buf ^ 1);   // prefetch next
        G128_COMPUTE(buf);                                // compute current
        __syncthreads();    // drains prefetch (issued before 16 MFMA) +
                            // protects buf reuse next iteration
        buf ^= 1;
    }
#undef G128_STAGE
#undef G128_COMPUTE
}

// Fused Q/K/V projections: z picks which. Output bf16 (B,T,D).
__global__ __launch_bounds__(256) void proj_gemm(
    const ushort_t* __restrict__ qb, const ushort_t* __restrict__ kb, const ushort_t* __restrict__ vb,
    const ushort_t* __restrict__ Wqb, const ushort_t* __restrict__ Wkb, const ushort_t* __restrict__ Wvb,
    const float* __restrict__ bq, const float* __restrict__ bk, const float* __restrict__ bv,
    ushort_t* __restrict__ qh, ushort_t* __restrict__ kh, ushort_t* __restrict__ vh)
{
    __shared__ ushort_t Asm[2][128 * 32];
    __shared__ ushort_t Bsm[2][128 * 32];
    const int z = blockIdx.z;
    const ushort_t* A = (z == 0) ? qb : (z == 1) ? kb : vb;
    const ushort_t* W = (z == 0) ? Wqb : (z == 1) ? Wkb : Wvb;
    const float* bias = (z == 0) ? bq : (z == 1) ? bk : bv;
    ushort_t* Y = (z == 0) ? qh : (z == 1) ? kh : vh;

    const int bm = blockIdx.y * 128, bn = blockIdx.x * 128;
    f32x4 acc[4][4];
    #pragma unroll
    for (int i = 0; i < 4; i++)
        #pragma unroll
        for (int j = 0; j < 4; j++) acc[i][j] = (f32x4)(0.f);

    gemm128_mainloop(A + (size_t)bm * DD, W + (size_t)bn * DD, DD, Asm, Bsm, acc);

    const int lane = threadIdx.x & 63, wave = threadIdx.x >> 6;
    const int mblk = (wave >> 1) * 64, nblk = (wave & 1) * 64;
    const int l15 = lane & 15, q = lane >> 4;
    #pragma unroll
    for (int mi = 0; mi < 4; mi++) {
        #pragma unroll
        for (int ni = 0; ni < 4; ni++) {
            int col = bn + nblk + ni * 16 + l15;
            float bcol = bias[col];
            #pragma unroll
            for (int r = 0; r < 4; r++) {
                int row = bm + mblk + mi * 16 + q * 4 + r;
                Y[(size_t)row * DD + col] = f2b(acc[mi][ni][r] + bcol);
            }
        }
    }
}

// Output projection: bf16 in, fp32 out + bias.
__global__ __launch_bounds__(256) void oproj_gemm(
    const ushort_t* __restrict__ A, const ushort_t* __restrict__ W,
    const float* __restrict__ bias, float* __restrict__ Y)
{
    __shared__ ushort_t Asm[2][128 * 32];
    __shared__ ushort_t Bsm[2][128 * 32];
    const int bm = blockIdx.y * 128, bn = blockIdx.x * 128;
    f32x4 acc[4][4];
    #pragma unroll
    for (int i = 0; i < 4; i++)
        #pragma unroll
        for (int j = 0; j < 4; j++) acc[i][j] = (f32x4)(0.f);

    gemm128_mainloop(A + (size_t)bm * DD, W + (size_t)bn * DD, DD, Asm, Bsm, acc);

    const int lane = threadIdx.x & 63, wave = threadIdx.x >> 6;
    const int mblk = (wave >> 1) * 64, nblk = (wave & 1) * 64;
    const int l15 = lane & 15, q = lane >> 4;
    #pragma unroll
    for (int mi = 0; mi < 4; mi++) {
        #pragma unroll
        for (int ni = 0; ni < 4; ni++) {
            int col = bn + nblk + ni * 16 + l15;
            float bcol = bias[col];
            #pragma unroll
            for (int r = 0; r < 4; r++) {
                int row = bm + mblk + mi * 16 + q * 4 + r;
                Y[(size_t)row * DD + col] = acc[mi][ni][r] + bcol;
            }
        }
    }
}

// ---------------------------------------------------------------------------
// V transpose: vh (B,S,H,DH) bf16 -> vT (B,H,DH,S) bf16
// ---------------------------------------------------------------------------
__global__ __launch_bounds__(256) void transpose_v(
    const ushort_t* __restrict__ vh, ushort_t* __restrict__ vT)
{
    __shared__ ushort_t Ls[64][72];
    const int s0 = blockIdx.x * 64;
    const int bh = blockIdx.y;
    const int b = bh >> 4, h = bh & 15;
    const int tid = threadIdx.x;
    const int r = tid >> 2, c16 = (tid & 3) * 16;

    const ushort_t* src = &vh[((size_t)(b * SS + s0 + r) * HH + h) * DH + c16];
    uint4 u0 = *(const uint4*)src;
    uint4 u1 = *(const uint4*)(src + 8);
    ushort_t tmp[16];
    *(uint4*)&tmp[0] = u0; *(uint4*)&tmp[8] = u1;
    #pragma unroll
    for (int j = 0; j < 16; j++) Ls[c16 + j][r] = tmp[j];
    __syncthreads();

    const int dh = r;
    uint4 w0 = *(const uint4*)&Ls[dh][c16];
    uint4 w1 = *(const uint4*)&Ls[dh][c16 + 8];
    ushort_t* dst = &vT[((size_t)bh * DH + dh) * SS + s0 + c16];
    *(uint4*)dst = w0;
    *(uint4*)(dst + 8) = w1;
}

// ---------------------------------------------------------------------------
// scores: attn_raw[bh,t,s] = clip(qh.kh/8). 128x128 tile per block, causal
// tiles only. K=64 (one-shot staging, 2 MFMA k-steps).
// ---------------------------------------------------------------------------
__global__ __launch_bounds__(256) void scores_mfma(
    const ushort_t* __restrict__ qh, const ushort_t* __restrict__ kh,
    float* __restrict__ attn)
{
    __shared__ ushort_t Qs[128 * 64];
    __shared__ ushort_t Ks[128 * 64];

    int idx = blockIdx.x, ti = 0;
    while (idx >= ti + 1) { idx -= ti + 1; ti++; }
    const int si = idx;
    const int bh = blockIdx.y;
    const int b = bh >> 4, h = bh & 15;
    const int t0 = ti * 128, s0 = si * 128;

    const int tid = threadIdx.x;
    const int wave = tid >> 6, lane = tid & 63;
    const int sr8 = lane >> 3;                 // 0..7: row within 8-row group
    const int gc8 = (lane & 7) ^ sr8;          // swizzled chunk (8 x 16B per row)

    #pragma unroll
    for (int o = 0; o < 4; o++) {
        int r0 = (wave * 4 + o) * 8;
        int r = r0 + sr8;
        __builtin_amdgcn_global_load_lds(
            AS1(qh + ((size_t)(b * TT + t0 + r) * HH + h) * DH + gc8 * 8),
            AS3(Qs + r0 * 64), 16, 0, 0);
        __builtin_amdgcn_global_load_lds(
            AS1(kh + ((size_t)(b * SS + s0 + r) * HH + h) * DH + gc8 * 8),
            AS3(Ks + r0 * 64), 16, 0, 0);
    }
    __syncthreads();

    const int l15 = lane & 15, q = lane >> 4;
    const int tblk = (wave >> 1) * 64, sblk = (wave & 1) * 64;
    f32x4 acc[4][4];
    #pragma unroll
    for (int i = 0; i < 4; i++)
        #pragma unroll
        for (int j = 0; j < 4; j++) acc[i][j] = (f32x4)(0.f);

    #pragma unroll
    for (int ks = 0; ks < 2; ks++) {
        bf16x8 av[4], bv[4];
        #pragma unroll
        for (int mi = 0; mi < 4; mi++) {
            int r = tblk + mi * 16 + l15;
            av[mi] = *(const bf16x8*)&Qs[r * 64 + ((ks * 4 + q) ^ (r & 7)) * 8];
        }
        #pragma unroll
        for (int ni = 0; ni < 4; ni++) {
            int r = sblk + ni * 16 + l15;
            bv[ni] = *(const bf16x8*)&Ks[r * 64 + ((ks * 4 + q) ^ (r & 7)) * 8];
        }
        #pragma unroll
        for (int mi = 0; mi < 4; mi++)
            #pragma unroll
            for (int ni = 0; ni < 4; ni++)
                acc[mi][ni] = __builtin_amdgcn_mfma_f32_16x16x32_bf16(av[mi], bv[ni], acc[mi][ni], 0, 0, 0);
    }

    #pragma unroll
    for (int mi = 0; mi < 4; mi++) {
        #pragma unroll
        for (int ni = 0; ni < 4; ni++) {
            int scol = s0 + sblk + ni * 16 + l15;
            #pragma unroll
            for (int r = 0; r < 4; r++) {
                int t = t0 + tblk + mi * 16 + q * 4 + r;
                float v = acc[mi][ni][r] * 0.125f;
                v = fminf(fmaxf(v, -80.f), 80.f);
                attn[((size_t)bh * TT + t) * SS + scol] = v;
            }
        }
    }
}

// ---------------------------------------------------------------------------
// softmax + multiplicative tanh bias + renormalize: ONE WAVE PER ROW.
// 4 waves/block, row fully in registers (16 f32/lane), all reductions via
// __shfl_xor (no barriers, no LDS). Bias loads ISSUED UP FRONT so their HBM
// latency hides under the max-reduce shuffle chain.
// ---------------------------------------------------------------------------
__global__ __launch_bounds__(256) void softmax_bias_wave(
    const float* __restrict__ attn_bias, const float* __restrict__ bias_scale_p,
    float* __restrict__ attn)
{
    const int wave = threadIdx.x >> 6, lane = threadIdx.x & 63;
    const int row = blockIdx.x * 4 + wave;          // (bh*TT + t), 0..32767
    const int t = row & (TT - 1);

    float* prow = attn + (size_t)row * SS;
    const float* brow = attn_bias + (size_t)row * SS;
    const float bscale = bias_scale_p[0];

    const int nc = (t >> 8) + 1;   // # of 256-wide chunks containing s <= t

    // issue score AND bias loads up front (bias latency hides under reduce)
    float v[16];
    float4 bx[4];
    float m = -INFINITY;
    #pragma unroll
    for (int c = 0; c < 4; c++) {
        const int s0 = c * 256 + lane * 4;
        if (c < nc) {                      // wave-uniform branch
            float4 rv = *(const float4*)&prow[s0];
            bx[c] = *(const float4*)&brow[s0];
            v[c * 4 + 0] = (s0     <= t) ? rv.x : -INFINITY;
            v[c * 4 + 1] = (s0 + 1 <= t) ? rv.y : -INFINITY;
            v[c * 4 + 2] = (s0 + 2 <= t) ? rv.z : -INFINITY;
            v[c * 4 + 3] = (s0 + 3 <= t) ? rv.w : -INFINITY;
            m = fmaxf(m, fmaxf(fmaxf(v[c*4], v[c*4+1]), fmaxf(v[c*4+2], v[c*4+3])));
        } else {
            v[c * 4 + 0] = -INFINITY; v[c * 4 + 1] = -INFINITY;
            v[c * 4 + 2] = -INFINITY; v[c * 4 + 3] = -INFINITY;
            bx[c] = make_float4(0.f, 0.f, 0.f, 0.f);
        }
    }
    #pragma unroll
    for (int off = 1; off < 64; off <<= 1)
        m = fmaxf(m, __shfl_xor(m, off));

    // p = exp(v-m); sc = 1 + bscale*tanh(bias); w = p*sc; accumulate P, W
    float w[16];
    float P = 0.f, Wn = 0.f;
    #pragma unroll
    for (int c = 0; c < 4; c++) {
        if (c < nc) {
            float bxx[4] = {bx[c].x, bx[c].y, bx[c].z, bx[c].w};
            #pragma unroll
            for (int j = 0; j < 4; j++) {
                float vv = v[c * 4 + j];
                float p = (vv > -INFINITY) ? __expf(vv - m) : 0.f;
                float e = __expf(-2.f * fabsf(bxx[j]));
                float th = copysignf((1.f - e) / (1.f + e), bxx[j]);
                float sc = fmaxf(1.f + bscale * th, 1e-9f);
                float ww = p * sc;
                w[c * 4 + j] = ww;
                P += p; Wn += ww;
            }
        } else {
            w[c * 4 + 0] = 0.f; w[c * 4 + 1] = 0.f;
            w[c * 4 + 2] = 0.f; w[c * 4 + 3] = 0.f;
        }
    }
    #pragma unroll
    for (int off = 1; off < 64; off <<= 1) {
        P  += __shfl_xor(P, off);
        Wn += __shfl_xor(Wn, off);
    }
    // final = p*sc / (Σp*sc + 1e-9*Σp)  ==  softmax*scale renormalized (+eps)
    const float inv = 1.f / (Wn + 1e-9f * P);

    #pragma unroll
    for (int c = 0; c < 4; c++) {
        const int s0 = c * 256 + lane * 4;
        float4 o;
        o.x = w[c * 4 + 0] * inv; o.y = w[c * 4 + 1] * inv;
        o.z = w[c * 4 + 2] * inv; o.w = w[c * 4 + 3] * inv;
        *(float4*)&prow[s0] = o;
    }
}

// ---------------------------------------------------------------------------
// AV: ao[b,t,h*64+dh] = sum_s attn[bh,t,s] * V[s,dh].  64t x 64dh per block.
// 64-wide s-steps. A-fragments read DIRECTLY from global fp32 (MFMA A-layout
// = 2x float4 per lane) + v_cvt_pk_bf16_f32; V double-buffered in LDS via
// global_load_lds (T3-minimal: stage(t+1) -> compute(t) -> one barrier).
// attn has exact zeros for s>t, so full diagonal tiles are safe.
// ---------------------------------------------------------------------------
__global__ __launch_bounds__(256) void av_mfma(
    const float* __restrict__ attn, const ushort_t* __restrict__ vT,
    ushort_t* __restrict__ ao)
{
    __shared__ ushort_t Vsm[2][64 * 64];   // 2 x 8 KB, XOR-chunk swizzled

    const int tb = (int)gridDim.x - 1 - (int)blockIdx.x;   // heavy blocks first
    const int bh = blockIdx.y;
    const int b = bh >> 4, h = bh & 15;
    const int t0 = tb * 64;
    const int nsteps = tb + 1;             // 64-wide s-steps covering s <= t

    const int tid = threadIdx.x;
    const int wave = tid >> 6, lane = tid & 63;
    const int sr8 = lane >> 3, gc8 = (lane & 7) ^ sr8;
    const int l15 = lane & 15, q = lane >> 4;

    // this lane's A-row pointer (t-row = t0 + wave*16 + l15), k-offset q*8
    const float* arow = attn + ((size_t)bh * TT + t0 + wave * 16 + l15) * SS + q * 8;
    const ushort_t* vbase = vT + (size_t)bh * DH * SS;

    f32x4 acc[4];
    #pragma unroll
    for (int i = 0; i < 4; i++) acc[i] = (f32x4)(0.f);

#define STAGE_V(sidx, buf) do {                                               \
        int s0_ = (sidx) * 64;                                                \
        _Pragma("unroll")                                                     \
        for (int o = 0; o < 2; o++) {                                         \
            int r0 = wave * 16 + o * 8;                                       \
            __builtin_amdgcn_global_load_lds(                                 \
                AS1(vbase + (size_t)(r0 + sr8) * SS + s0_ + gc8 * 8),         \
                AS3(&Vsm[buf][r0 * 64]), 16, 0, 0);                           \
        } } while (0)

#define LOAD_A(sidx, dst) do {                                                \
        const float* p_ = arow + (sidx) * 64;                                 \
        dst[0] = *(const float4*)(p_);                                        \
        dst[1] = *(const float4*)(p_ + 4);                                    \
        dst[2] = *(const float4*)(p_ + 32);                                   \
        dst[3] = *(const float4*)(p_ + 36); } while (0)

#define COMPUTE(buf, ax) do {                                                 \
        bf16x8 af0 = pack_bf16x8(ax[0], ax[1]);                               \
        bf16x8 af1 = pack_bf16x8(ax[2], ax[3]);                               \
        _Pragma("unroll")                                                     \
        for (int ni = 0; ni < 4; ni++) {                                      \
            int rv = ni * 16 + l15;                                           \
            bf16x8 b0 = *(const bf16x8*)&Vsm[buf][rv * 64 + ((q) ^ (rv & 7)) * 8];       \
            bf16x8 b1 = *(const bf16x8*)&Vsm[buf][rv * 64 + ((4 + q) ^ (rv & 7)) * 8];   \
            acc[ni] = __builtin_amdgcn_mfma_f32_16x16x32_bf16(af0, b0, acc[ni], 0, 0, 0);\
            acc[ni] = __builtin_amdgcn_mfma_f32_16x16x32_bf16(af1, b1, acc[ni], 0, 0, 0);\
        } } while (0)

    float4 aA[4], aB[4];
    STAGE_V(0, 0);
    LOAD_A(0, aA);
    __syncthreads();

    int st = 0;
    while (true) {
        if (st + 1 < nsteps) { STAGE_V(st + 1, 1); LOAD_A(st + 1, aB); }
        COMPUTE(0, aA);
        __syncthreads();
        if (++st == nsteps) break;
        if (st + 1 < nsteps) { STAGE_V(st + 1, 0); LOAD_A(st + 1, aA); }
        COMPUTE(1, aB);
        __syncthreads();
        if (++st == nsteps) break;
    }

#undef STAGE_V
#undef LOAD_A
#undef COMPUTE

    #pragma unroll
    for (int ni = 0; ni < 4; ni++) {
        int dh = ni * 16 + l15;
        #pragma unroll
        for (int r = 0; r < 4; r++) {
            int t = t0 + wave * 16 + q * 4 + r;
            ao[(size_t)(b * TT + t) * DD + h * DH + dh] = f2b(acc[ni][r]);
        }
    }
}

// ---------------------------------------------------------------------------
extern "C" void kernel_launch(void* const* d_in, const int* in_sizes, int n_in,
                              void* d_out, int out_size, void* d_ws, size_t ws_size,
                              hipStream_t stream)
{
    const float* q   = (const float*)d_in[0];
    const float* k   = (const float*)d_in[1];
    const float* v   = (const float*)d_in[2];
    const float* attn_bias = (const float*)d_in[4];
    const float* Wq = (const float*)d_in[5];
    const float* bq = (const float*)d_in[6];
    const float* Wk = (const float*)d_in[7];
    const float* bk = (const float*)d_in[8];
    const float* Wv = (const float*)d_in[9];
    const float* bv = (const float*)d_in[10];
    const float* Wo = (const float*)d_in[11];
    const float* bo = (const float*)d_in[12];
    const float* bscale = (const float*)d_in[13];

    // ws layout (32 MB total, with aliasing):
    char* base = (char*)d_ws;
    ushort_t* qb  = (ushort_t*)(base + (0ull << 20));   // 4 MB, later vT
    ushort_t* kb  = (ushort_t*)(base + (4ull << 20));   // 4 MB, later ao
    ushort_t* vb  = (ushort_t*)(base + (8ull << 20));   // 4 MB
    ushort_t* Wqb = (ushort_t*)(base + (12ull << 20));  // 2 MB
    ushort_t* Wkb = (ushort_t*)(base + (14ull << 20));  // 2 MB
    ushort_t* Wvb = (ushort_t*)(base + (16ull << 20));  // 2 MB
    ushort_t* Wob = (ushort_t*)(base + (18ull << 20));  // 2 MB
    ushort_t* qhb = (ushort_t*)(base + (20ull << 20));  // 4 MB
    ushort_t* khb = (ushort_t*)(base + (24ull << 20));  // 4 MB
    ushort_t* vhb = (ushort_t*)(base + (28ull << 20));  // 4 MB
    ushort_t* vT  = qb;   // alias: qb dead after proj_gemm
    ushort_t* aob = kb;   // alias: kb dead after proj_gemm

    float* out  = (float*)d_out;
    float* attn = out + (size_t)BB * TT * DD;

    cvt_all<<<dim3(1024, 7), 256, 0, stream>>>(q, k, v, Wq, Wk, Wv, Wo,
                                               qb, kb, vb, Wqb, Wkb, Wvb, Wob);
    proj_gemm<<<dim3(8, 16, 3), 256, 0, stream>>>(qb, kb, vb, Wqb, Wkb, Wvb,
                                                  bq, bk, bv, qhb, khb, vhb);
    transpose_v<<<dim3(16, 32), 256, 0, stream>>>(vhb, vT);
    scores_mfma<<<dim3(36, 32), 256, 0, stream>>>(qhb, khb, attn);
    softmax_bias_wave<<<dim3(8192), 256, 0, stream>>>(attn_bias, bscale, attn);
    av_mfma<<<dim3(16, 32), 256, 0, stream>>>(attn, vT, aob);
    oproj_gemm<<<dim3(8, 16), 256, 0, stream>>>(aob, Wob, bo, out);
}